// Round 1
// baseline (6074.395 us; speedup 1.0000x reference)
//
#include <hip/hip_runtime.h>
#include <math.h>

#define B_   64
#define N_   1024
#define D_   128
#define DP1  129
#define XPAD 132        // x row padded to 132 floats (16B-aligned, good b128 banking)
#define NC_  10
#define QT   4          // queries per block (1 per wave)
#define JT   64         // key tile

static __device__ __forceinline__ double wave_allreduce_add(double v) {
    #pragma unroll
    for (int off = 32; off > 0; off >>= 1) v += __shfl_xor(v, off, 64);
    return v;
}

// ---------------- Wo transpose: WoT[d][o] = Wo[o][d] ----------------
__global__ __launch_bounds__(128) void k_transpose_wo(const float* __restrict__ Wo,
                                                      float* __restrict__ WoT) {
    int d = blockIdx.x;   // 0..128
    int o = threadIdx.x;  // 0..127
    WoT[d * D_ + o] = Wo[o * DP1 + d];
}

// ---------------- mask dtype detection (int32 vs packed int8 bool) ----------------
__global__ __launch_bounds__(256) void k_detect_mask(const int* __restrict__ mask_w,
                                                     int* __restrict__ flag) {
    __shared__ int bad;
    if (threadIdx.x == 0) bad = 0;
    __syncthreads();
    int local = 0;
    // scan first 16384 words (safe under both interpretations)
    for (int i = threadIdx.x; i < 16384; i += 256) {
        int v = mask_w[i];
        if (v != 0 && v != 1) local = 1;
    }
    if (local) atomicOr(&bad, 1);
    __syncthreads();
    if (threadIdx.x == 0) *flag = bad;   // 1 => data is packed int8 bools
}

static __device__ __forceinline__ int read_mask(const int* mw, int is_i8, int idx) {
    if (is_i8) return (int)((const unsigned char*)mw)[idx];
    return mw[idx];
}

// ---------------- embedding lookup + Lorentz expmap0 ----------------
__global__ __launch_bounds__(64) void k_embed(const int* __restrict__ tok,
                                              const float* __restrict__ emb,
                                              float* __restrict__ X) {
    const int row = blockIdx.x;      // b*N + n
    const int l   = threadIdx.x;     // 0..63, handles comps 2l, 2l+1 of v
    const int t   = tok[row];
    const float2 v = ((const float2*)(emb + (size_t)t * D_))[l];
    double s = (double)v.x * v.x + (double)v.y * v.y;
    s = wave_allreduce_add(s);
    double nv = sqrt(s);
    if (nv < 1e-7) nv = 1e-7;
    const double SCd = 0.31622776601683794;  // sqrt(0.1)
    double a    = SCd * nv;
    double coef = sinh(a) / (SCd * nv);
    float* xr = X + (size_t)row * XPAD;
    if (l == 0) xr[0] = (float)(cosh(a) / SCd);
    xr[1 + 2 * l] = (float)(v.x * coef);
    xr[2 + 2 * l] = (float)(v.y * coef);
    if (l < 3) xr[DP1 + l] = 0.f;            // zero pad
}

// ---------------- fused attention + centroid + projection + Poincare expmap ----------------
__global__ __launch_bounds__(256) void k_attn(const float* __restrict__ X,
                                              const int* __restrict__ mask,
                                              const int* __restrict__ mflag,
                                              const float* __restrict__ WoT,
                                              const float* __restrict__ bo,
                                              float* __restrict__ Y) {
    __shared__ float  Ks[JT][XPAD];      // 33792 B
    __shared__ float  Qs[QT][XPAD];      //  2112 B
    __shared__ float  Es[QT][JT];        //  1024 B
    __shared__ double MuB[QT][DP1 + 1];  //  4160 B

    const int b   = blockIdx.y;
    const int i0  = blockIdx.x * QT;
    const int tid = threadIdx.x;
    const int w   = tid >> 6;   // wave id == query within block
    const int l   = tid & 63;
    const int is8 = *mflag;

    // stage Q rows with sign flip (time comp +, spatial -): score = q . k then /sqrt(129)
    for (int idx = tid; idx < QT * XPAD; idx += 256) {
        int q = idx / XPAD, d = idx - q * XPAD;
        float vx = (d < DP1) ? X[((size_t)(b * N_ + i0 + q)) * XPAD + d] : 0.f;
        Qs[q][d] = (d == 0) ? vx : -vx;
    }

    double mua = 0.0, mub = 0.0, mu128 = 0.0, lsum = 0.0;

    for (int jt = 0; jt < N_ / JT; ++jt) {
        __syncthreads();   // protect previous tile reads
        {
            const float4* src = (const float4*)(X + ((size_t)(b * N_ + jt * JT)) * XPAD);
            float4* dst = (float4*)(&Ks[0][0]);
            for (int idx = tid; idx < JT * XPAD / 4; idx += 256) dst[idx] = src[idx];
        }
        __syncthreads();

        // phase A: score for key j = jt*64 + l
        float sc_ = 0.f;
        {
            const float4* Kr = (const float4*)(&Ks[l][0]);
            const float4* Qr = (const float4*)(&Qs[w][0]);
            #pragma unroll
            for (int t4 = 0; t4 < XPAD / 4; ++t4) {
                float4 kv = Kr[t4], qv = Qr[t4];
                sc_ += kv.x * qv.x + kv.y * qv.y + kv.z * qv.z + kv.w * qv.w;
            }
        }
        sc_ *= 0.08804509063256238f;  // 1/sqrt(129)
        const int m = read_mask(mask, is8, b * N_ + jt * JT + l);
        const float e = m ? expf(sc_) : 0.f;
        Es[w][l] = e;
        lsum += (double)e;

        // phase B: mu += e_j * x_j   (lane owns comps 2l, 2l+1; comp 128 replicated)
        #pragma unroll 4
        for (int j = 0; j < JT; ++j) {
            float wgt  = Es[w][j];
            float2 kv  = *(const float2*)(&Ks[j][2 * l]);
            float k128 = Ks[j][D_];
            mua   += (double)wgt * kv.x;
            mub   += (double)wgt * kv.y;
            mu128 += (double)wgt * k128;
        }
    }

    // softmax denominator + Lorentz centroid renormalization
    double lT = wave_allreduce_add(lsum);
    if (!(lT > 0.0)) lT = 1.0;                 // unreachable guard (cnt>0 for all batches)
    double m0 = mua / lT, m1 = mub / lT, m2 = mu128 / lT;
    // inner = -mu0^2 + sum_{d>=1} mu_d^2 ; lane0 holds d=0 (time) and d=1
    double p = (l == 0) ? (m1 * m1 - m0 * m0) : (m0 * m0 + m1 * m1);
    double inner = wave_allreduce_add(p) + m2 * m2;
    double neg = -inner;
    if (neg < 1e-7) neg = 1e-7;
    const double SCd = 0.31622776601683794;
    double dn = SCd * sqrt(neg);
    m0 /= dn; m1 /= dn; m2 /= dn;
    MuB[w][2 * l] = m0;
    MuB[w][2 * l + 1] = m1;
    if (l == 0) MuB[w][D_] = m2;

    // u = mu . Wo^T + bo  (lane computes outputs o=2l, 2l+1)
    double uu0 = (double)bo[2 * l], uu1 = (double)bo[2 * l + 1];
    for (int d = 0; d < DP1; ++d) {
        double md = MuB[w][d];
        float2 wv = *(const float2*)(WoT + (size_t)d * D_ + 2 * l);
        uu0 += md * (double)wv.x;
        uu1 += md * (double)wv.y;
    }
    // Poincare expmap0
    double nn = wave_allreduce_add(uu0 * uu0 + uu1 * uu1);
    double nu = sqrt(nn);
    if (nu < 1e-7) nu = 1e-7;
    double a2 = SCd * nu;
    double cf = tanh(a2) / a2;
    float2 yv;
    yv.x = (float)(uu0 * cf);
    yv.y = (float)(uu1 * cf);
    *(float2*)(Y + ((size_t)(b * N_ + i0 + w)) * D_ + 2 * l) = yv;
}

// ---------------- sequential Mobius fold + scalarmul + logmap + MLR head ----------------
__global__ __launch_bounds__(64) void k_pool(const float* __restrict__ Y,
                                             const int* __restrict__ mask,
                                             const int* __restrict__ mflag,
                                             const float* __restrict__ Wf,
                                             const float* __restrict__ bf,
                                             float* __restrict__ out) {
    __shared__ double vb[D_];
    const int b = blockIdx.x;
    const int l = threadIdx.x;            // lane owns comps 2l, 2l+1
    const int is8 = *mflag;
    const double c = 0.1;
    const double SCd = 0.31622776601683794;

    double a0 = 0.0, a1 = 0.0, x2 = 0.0;  // acc and its squared norm (propagated analytically)
    int cnt = 0;
    for (int i = 0; i < N_; ++i) {
        if (!read_mask(mask, is8, b * N_ + i)) continue;   // wave-uniform branch
        ++cnt;
        float2 yv = *(const float2*)(Y + ((size_t)(b * N_ + i)) * D_ + 2 * l);
        double y0 = yv.x, y1 = yv.y;
        double pxy = a0 * y0 + a1 * y1;
        double py2 = y0 * y0 + y1 * y1;
        #pragma unroll
        for (int off = 32; off > 0; off >>= 1) {
            pxy += __shfl_xor(pxy, off, 64);
            py2 += __shfl_xor(py2, off, 64);
        }
        double A   = 1.0 + 2.0 * c * pxy + c * py2;
        double Bc  = 1.0 - c * x2;
        double den = 1.0 + 2.0 * c * pxy + c * c * x2 * py2;
        if (den < 1e-12) den = 1e-12;
        double inv = 1.0 / den;
        a0 = (A * a0 + Bc * y0) * inv;
        a1 = (A * a1 + Bc * y1) * inv;
        // |num|^2 = A^2 x2 + 2 A Bc xy + Bc^2 y2   (exact identity)
        x2 = (A * A * x2 + 2.0 * A * Bc * pxy + Bc * Bc * py2) * (inv * inv);
    }

    // mobius_scalarmul(1/cnt, acc)
    double p2 = a0 * a0 + a1 * a1;
    p2 = wave_allreduce_add(p2);
    double n = sqrt(p2);
    double t = SCd * n;
    if (t < 1e-7) t = 1e-7;
    if (t > 1.0 - 1e-6) t = 1.0 - 1e-6;
    int cm = cnt > 0 ? cnt : 1;
    float rf = (float)(1.0 / (double)cm);         // ref casts r to float32
    double r = (double)rf;
    double dv = SCd * n;
    if (dv < 1e-7) dv = 1e-7;
    double f = tanh(r * atanh(t)) / dv;
    double p0 = a0 * f, p1 = a1 * f;
    if (cnt == 0) {                               // fallback: first token's y
        float2 y0v = *(const float2*)(Y + ((size_t)(b * N_)) * D_ + 2 * l);
        p0 = y0v.x; p1 = y0v.y;
    }

    // Poincare logmap0
    double q2 = p0 * p0 + p1 * p1;
    q2 = wave_allreduce_add(q2);
    double npn = sqrt(q2);
    if (npn < 1e-7) npn = 1e-7;
    double t2 = SCd * npn;
    if (t2 < 1e-7) t2 = 1e-7;
    if (t2 > 1.0 - 1e-6) t2 = 1.0 - 1e-6;
    double f2 = atanh(t2) / (SCd * npn);
    vb[2 * l]     = p0 * f2;
    vb[2 * l + 1] = p1 * f2;
    __syncthreads();

    if (l < NC_) {
        double o = (double)bf[l];
        for (int d = 0; d < D_; ++d) o += vb[d] * (double)Wf[l * D_ + d];
        out[b * NC_ + l] = (float)o;
    }
}

extern "C" void kernel_launch(void* const* d_in, const int* in_sizes, int n_in,
                              void* d_out, int out_size, void* d_ws, size_t ws_size,
                              hipStream_t stream) {
    const int*   tok  = (const int*)d_in[0];
    const int*   mask = (const int*)d_in[1];
    const float* emb  = (const float*)d_in[2];
    const float* Wo   = (const float*)d_in[3];
    const float* bo   = (const float*)d_in[4];
    const float* Wf   = (const float*)d_in[5];
    const float* bf   = (const float*)d_in[6];
    float* out = (float*)d_out;

    float* X    = (float*)d_ws;                       // 64*1024*132 floats
    float* Y    = X + (size_t)B_ * N_ * XPAD;         // 64*1024*128 floats
    float* WoT  = Y + (size_t)B_ * N_ * D_;           // 129*128 floats
    int*   flag = (int*)(WoT + (size_t)DP1 * D_);     // 1 int

    k_detect_mask<<<dim3(1), dim3(256), 0, stream>>>(mask, flag);
    k_transpose_wo<<<dim3(DP1), dim3(D_), 0, stream>>>(Wo, WoT);
    k_embed<<<dim3(B_ * N_), dim3(64), 0, stream>>>(tok, emb, X);
    k_attn<<<dim3(N_ / QT, B_), dim3(256), 0, stream>>>(X, mask, flag, WoT, bo, Y);
    k_pool<<<dim3(B_), dim3(64), 0, stream>>>(Y, mask, flag, Wf, bf, out);
}

// Round 2
// 1103.259 us; speedup vs baseline: 5.5059x; 5.5059x over previous
//
#include <hip/hip_runtime.h>
#include <math.h>

#define B_   64
#define N_   1024
#define D_   128
#define DP1  129
#define XPAD 132        // x row padded to 132 floats (16B-aligned rows)
#define NC_  10
#define GQ   8          // queries per wave
#define QB   32         // queries per block (4 waves * GQ)
#define JT   64         // key tile

typedef float v2f __attribute__((ext_vector_type(2)));

static __device__ __forceinline__ double wave_red_f64(double v) {
    #pragma unroll
    for (int o = 32; o > 0; o >>= 1) v += __shfl_xor(v, o, 64);
    return v;
}
static __device__ __forceinline__ float wave_red_f32(float v) {
    #pragma unroll
    for (int o = 32; o > 0; o >>= 1) v += __shfl_xor(v, o, 64);
    return v;
}

// ---------------- Wo transpose: WoT[d][o] = Wo[o][d] ----------------
__global__ __launch_bounds__(128) void k_transpose_wo(const float* __restrict__ Wo,
                                                      float* __restrict__ WoT) {
    int d = blockIdx.x;   // 0..128
    int o = threadIdx.x;  // 0..127
    WoT[d * D_ + o] = Wo[o * DP1 + d];
}

// ---------------- mask dtype detection (int32 vs packed int8 bool) ----------------
__global__ __launch_bounds__(256) void k_detect_mask(const int* __restrict__ mask_w,
                                                     int* __restrict__ flag) {
    __shared__ int bad;
    if (threadIdx.x == 0) bad = 0;
    __syncthreads();
    int local = 0;
    for (int i = threadIdx.x; i < 16384; i += 256) {
        int v = mask_w[i];
        if (v != 0 && v != 1) local = 1;
    }
    if (local) atomicOr(&bad, 1);
    __syncthreads();
    if (threadIdx.x == 0) *flag = bad;   // 1 => data is packed int8 bools
}

static __device__ __forceinline__ int read_mask(const int* mw, int is_i8, int idx) {
    if (is_i8) return (int)((const unsigned char*)mw)[idx];
    return mw[idx];
}

// ---------------- embedding lookup + Lorentz expmap0 ----------------
__global__ __launch_bounds__(64) void k_embed(const int* __restrict__ tok,
                                              const float* __restrict__ emb,
                                              float* __restrict__ X) {
    const int row = blockIdx.x;      // b*N + n
    const int l   = threadIdx.x;     // 0..63, handles comps 2l, 2l+1 of v
    const int t   = tok[row];
    const float2 v = ((const float2*)(emb + (size_t)t * D_))[l];
    double s = (double)v.x * v.x + (double)v.y * v.y;
    s = wave_red_f64(s);
    double nv = sqrt(s);
    if (nv < 1e-7) nv = 1e-7;
    const double SCd = 0.31622776601683794;  // sqrt(0.1)
    double a    = SCd * nv;
    double coef = sinh(a) / (SCd * nv);
    float* xr = X + (size_t)row * XPAD;
    if (l == 0) xr[0] = (float)(cosh(a) / SCd);
    xr[1 + 2 * l] = (float)(v.x * coef);
    xr[2 + 2 * l] = (float)(v.y * coef);
    if (l < 3) xr[DP1 + l] = 0.f;            // zero pad cols 129..131
}

// ---------------- fused attention + centroid + projection + Poincare expmap ----------------
__global__ __launch_bounds__(256) void k_attn(const float* __restrict__ X,
                                              const int* __restrict__ mask,
                                              const int* __restrict__ mflag,
                                              const float* __restrict__ WoT,
                                              const float* __restrict__ bo,
                                              float* __restrict__ Y) {
    __shared__ float Ks[JT][XPAD];      // 33792 B; aliased as mu staging after main loop
    __shared__ float Es[4][GQ][68];     //  8704 B; per-wave softmax weights (no barrier needed)

    const int b   = blockIdx.y;
    const int i0  = blockIdx.x * QB;
    const int tid = threadIdx.x;
    const int w   = tid >> 6;   // wave id
    const int l   = tid & 63;   // lane: phase A key index, phase B comp pair (2l,2l+1)
    const int is8 = *mflag;

    // wave-uniform Q pointer -> scalar-path loads
    const int qrow0 = __builtin_amdgcn_readfirstlane(b * N_ + i0 + w * GQ);
    const float*  __restrict__ Qp  = X + (size_t)qrow0 * XPAD;
    const float4* __restrict__ Qp4 = (const float4*)Qp;

    float qz[GQ];
    #pragma unroll
    for (int q = 0; q < GQ; ++q) qz[q] = Qp[q * XPAD];   // comp-0 (time) of each query

    v2f   mu2[GQ];          // f32 centroid accumulators, comps (2l, 2l+1)
    float p128[GQ];         // per-lane partial of comp-128 (lane = key)
    float lsm[GQ];          // per-lane partial of softmax denom
    #pragma unroll
    for (int q = 0; q < GQ; ++q) { mu2[q] = (v2f){0.f, 0.f}; p128[q] = 0.f; lsm[q] = 0.f; }

    const float scale = 0.08804509063256238f;  // 1/sqrt(129)

    for (int jt = 0; jt < N_ / JT; ++jt) {
        __syncthreads();   // protect previous tile reads
        {
            const float4* src = (const float4*)(X + (size_t)(b * N_ + jt * JT) * XPAD);
            float4* dst = (float4*)(&Ks[0][0]);
            for (int idx = tid; idx < JT * XPAD / 4; idx += 256) dst[idx] = src[idx];
        }
        __syncthreads();

        // ---- phase A: scores for 8 queries x key l ----
        v2f sc2[GQ];
        #pragma unroll
        for (int q = 0; q < GQ; ++q) sc2[q] = (v2f){0.f, 0.f};
        const float4* Kr = (const float4*)(&Ks[l][0]);
        for (int t4 = 0; t4 < XPAD / 4; ++t4) {
            float4 kv = Kr[t4];
            v2f ka = {kv.x, kv.y}, kb = {kv.z, kv.w};
            #pragma unroll
            for (int q = 0; q < GQ; ++q) {
                float4 qv = Qp4[q * (XPAD / 4) + t4];   // uniform address -> SMEM/L1 broadcast
                v2f qa = {qv.x, qv.y}, qb = {qv.z, qv.w};
                sc2[q] = __builtin_elementwise_fma(ka, qa, sc2[q]);
                sc2[q] = __builtin_elementwise_fma(kb, qb, sc2[q]);
            }
        }
        const float k0   = Ks[l][0];
        const float k128 = Ks[l][D_];
        const int   m    = read_mask(mask, is8, b * N_ + jt * JT + l);
        #pragma unroll
        for (int q = 0; q < GQ; ++q) {
            float dot = sc2[q].x + sc2[q].y;
            float sc  = (2.f * qz[q] * k0 - dot) * scale;  // Lorentz sign trick
            float e   = m ? expf(sc) : 0.f;
            Es[w][q][l] = e;
            lsm[q]  += e;
            p128[q] += e * k128;
        }
        // no barrier: Es written/read by the same wave only

        // ---- phase B: mu += e_j * x_j, lane owns comps (2l, 2l+1) ----
        for (int jg = 0; jg < JT / 4; ++jg) {
            float2 kv2[4];
            #pragma unroll
            for (int jj = 0; jj < 4; ++jj)
                kv2[jj] = *(const float2*)(&Ks[jg * 4 + jj][2 * l]);
            #pragma unroll
            for (int q = 0; q < GQ; ++q) {
                float4 ev = *(const float4*)(&Es[w][q][jg * 4]);  // 16B-aligned broadcast
                v2f e0 = {ev.x, ev.x}, e1 = {ev.y, ev.y}, e2 = {ev.z, ev.z}, e3 = {ev.w, ev.w};
                v2f k0v = {kv2[0].x, kv2[0].y}, k1v = {kv2[1].x, kv2[1].y};
                v2f k2v = {kv2[2].x, kv2[2].y}, k3v = {kv2[3].x, kv2[3].y};
                mu2[q] = __builtin_elementwise_fma(e0, k0v, mu2[q]);
                mu2[q] = __builtin_elementwise_fma(e1, k1v, mu2[q]);
                mu2[q] = __builtin_elementwise_fma(e2, k2v, mu2[q]);
                mu2[q] = __builtin_elementwise_fma(e3, k3v, mu2[q]);
            }
        }
    }

    // ---- reductions + Lorentz renormalize; stage mu into LDS (aliases Ks) ----
    __syncthreads();                     // everyone done with Ks as K-tile
    float* MuF = &Ks[0][0];              // row (w*GQ+q)*XPAD, 129 floats used
    const double SCd = 0.31622776601683794;
    #pragma unroll
    for (int q = 0; q < GQ; ++q) {
        float lT = wave_red_f32(lsm[q]);
        float mA = wave_red_f32(p128[q]);
        double inv_l = (lT > 0.f) ? 1.0 / (double)lT : 1.0;
        double m0 = (double)mu2[q].x * inv_l;
        double m1 = (double)mu2[q].y * inv_l;
        double mC = (double)mA * inv_l;                    // comp 128
        double p  = (l == 0) ? (m1 * m1 - m0 * m0) : (m0 * m0 + m1 * m1);
        double inner = wave_red_f64(p) + mC * mC;          // Lorentz inner <mu,mu>_L
        double neg = -inner;
        if (neg < 1e-7) neg = 1e-7;
        double dn = 1.0 / (SCd * sqrt(neg));
        float* mr = MuF + (size_t)(w * GQ + q) * XPAD;
        mr[2 * l]     = (float)(m0 * dn);
        mr[2 * l + 1] = (float)(m1 * dn);
        if (l == 0) mr[D_] = (float)(mC * dn);
    }
    // same-wave read-after-write on LDS: no barrier needed

    // ---- projection u = mu . Wo^T + bo  (lane owns outputs 2l, 2l+1) ----
    const float2 bo2 = *(const float2*)(bo + 2 * l);
    v2f uu[GQ];
    #pragma unroll
    for (int q = 0; q < GQ; ++q) uu[q] = (v2f){bo2.x, bo2.y};
    const float2* W2 = (const float2*)WoT;
    for (int d = 0; d < DP1; ++d) {
        float2 wv = W2[d * 64 + l];
        v2f wvv = {wv.x, wv.y};
        #pragma unroll
        for (int q = 0; q < GQ; ++q) {
            float md = MuF[(size_t)(w * GQ + q) * XPAD + d];   // LDS broadcast
            v2f ms = {md, md};
            uu[q] = __builtin_elementwise_fma(ms, wvv, uu[q]);
        }
    }

    // ---- Poincare expmap0 + store ----
    #pragma unroll
    for (int q = 0; q < GQ; ++q) {
        double u0 = uu[q].x, u1 = uu[q].y;
        double nn = wave_red_f64(u0 * u0 + u1 * u1);
        double nu = sqrt(nn);
        if (nu < 1e-7) nu = 1e-7;
        double a2 = SCd * nu;
        double cf = tanh(a2) / a2;       // tanh(sc*nu)/(sc*nu)
        float2 yv;
        yv.x = (float)(u0 * cf);
        yv.y = (float)(u1 * cf);
        *(float2*)(Y + (size_t)(b * N_ + i0 + w * GQ + q) * D_ + 2 * l) = yv;
    }
}

// ---------------- sequential Mobius fold + scalarmul + logmap + MLR head ----------------
__global__ __launch_bounds__(64) void k_pool(const float* __restrict__ Y,
                                             const int* __restrict__ mask,
                                             const int* __restrict__ mflag,
                                             const float* __restrict__ Wf,
                                             const float* __restrict__ bf,
                                             float* __restrict__ out) {
    __shared__ double vb[D_];
    const int b = blockIdx.x;
    const int l = threadIdx.x;            // lane owns comps 2l, 2l+1
    const int is8 = *mflag;
    const double c = 0.1;
    const double SCd = 0.31622776601683794;

    double a0 = 0.0, a1 = 0.0, x2 = 0.0;  // acc and its squared norm (propagated analytically)
    int cnt = 0;
    for (int i = 0; i < N_; ++i) {
        if (!read_mask(mask, is8, b * N_ + i)) continue;   // wave-uniform branch
        ++cnt;
        float2 yv = *(const float2*)(Y + (size_t)(b * N_ + i) * D_ + 2 * l);
        double y0 = yv.x, y1 = yv.y;
        double pxy = a0 * y0 + a1 * y1;
        double py2 = y0 * y0 + y1 * y1;
        #pragma unroll
        for (int off = 32; off > 0; off >>= 1) {
            pxy += __shfl_xor(pxy, off, 64);
            py2 += __shfl_xor(py2, off, 64);
        }
        double A   = 1.0 + 2.0 * c * pxy + c * py2;
        double Bc  = 1.0 - c * x2;
        double den = 1.0 + 2.0 * c * pxy + c * c * x2 * py2;
        if (den < 1e-12) den = 1e-12;
        double inv = 1.0 / den;
        a0 = (A * a0 + Bc * y0) * inv;
        a1 = (A * a1 + Bc * y1) * inv;
        x2 = (A * A * x2 + 2.0 * A * Bc * pxy + Bc * Bc * py2) * (inv * inv);
    }

    double p2 = a0 * a0 + a1 * a1;
    p2 = wave_red_f64(p2);
    double n = sqrt(p2);
    double t = SCd * n;
    if (t < 1e-7) t = 1e-7;
    if (t > 1.0 - 1e-6) t = 1.0 - 1e-6;
    int cm = cnt > 0 ? cnt : 1;
    float rf = (float)(1.0 / (double)cm);
    double r = (double)rf;
    double dv = SCd * n;
    if (dv < 1e-7) dv = 1e-7;
    double f = tanh(r * atanh(t)) / dv;
    double p0 = a0 * f, p1 = a1 * f;
    if (cnt == 0) {
        float2 y0v = *(const float2*)(Y + (size_t)(b * N_) * D_ + 2 * l);
        p0 = y0v.x; p1 = y0v.y;
    }

    double q2 = p0 * p0 + p1 * p1;
    q2 = wave_red_f64(q2);
    double npn = sqrt(q2);
    if (npn < 1e-7) npn = 1e-7;
    double t2 = SCd * npn;
    if (t2 < 1e-7) t2 = 1e-7;
    if (t2 > 1.0 - 1e-6) t2 = 1.0 - 1e-6;
    double f2 = atanh(t2) / (SCd * npn);
    vb[2 * l]     = p0 * f2;
    vb[2 * l + 1] = p1 * f2;
    __syncthreads();

    if (l < NC_) {
        double o = (double)bf[l];
        for (int d = 0; d < D_; ++d) o += vb[d] * (double)Wf[l * D_ + d];
        out[b * NC_ + l] = (float)o;
    }
}

extern "C" void kernel_launch(void* const* d_in, const int* in_sizes, int n_in,
                              void* d_out, int out_size, void* d_ws, size_t ws_size,
                              hipStream_t stream) {
    const int*   tok  = (const int*)d_in[0];
    const int*   mask = (const int*)d_in[1];
    const float* emb  = (const float*)d_in[2];
    const float* Wo   = (const float*)d_in[3];
    const float* bo   = (const float*)d_in[4];
    const float* Wf   = (const float*)d_in[5];
    const float* bf   = (const float*)d_in[6];
    float* out = (float*)d_out;

    float* X    = (float*)d_ws;                       // 64*1024*132 floats
    float* Y    = X + (size_t)B_ * N_ * XPAD;         // 64*1024*128 floats
    float* WoT  = Y + (size_t)B_ * N_ * D_;           // 129*128 floats
    int*   flag = (int*)(WoT + (size_t)DP1 * D_);     // 1 int

    k_detect_mask<<<dim3(1), dim3(256), 0, stream>>>(mask, flag);
    k_transpose_wo<<<dim3(DP1), dim3(D_), 0, stream>>>(Wo, WoT);
    k_embed<<<dim3(B_ * N_), dim3(64), 0, stream>>>(tok, emb, X);
    k_attn<<<dim3(N_ / QB, B_), dim3(256), 0, stream>>>(X, mask, flag, WoT, bo, Y);
    k_pool<<<dim3(B_), dim3(64), 0, stream>>>(Y, mask, flag, Wf, bf, out);
}

// Round 3
// 669.185 us; speedup vs baseline: 9.0773x; 1.6487x over previous
//
#include <hip/hip_runtime.h>
#include <math.h>

#define B_    64
#define N_    1024
#define D_    128
#define DP1   129
#define NC_   10
#define QB    128     // queries per block (4 waves x 32)
#define KT    32      // key tile
#define SCf   0.31622776601683794f
#define SCALE 0.08804509063256238f   // 1/sqrt(129)

typedef __bf16 bf16x8 __attribute__((ext_vector_type(8)));
typedef float  f32x16 __attribute__((ext_vector_type(16)));

#define MFMA(a, b, c) __builtin_amdgcn_mfma_f32_32x32x16_bf16((a), (b), (c), 0, 0, 0)

static __device__ __forceinline__ float dpp_add_step(float f, int ctrl, int rmask) {
    // moved = dpp(f); lanes not written get old=0; add.
    if (ctrl == 0x111) { int t = __builtin_amdgcn_update_dpp(0, __builtin_bit_cast(int, f), 0x111, 0xf, 0xf, true); return f + __builtin_bit_cast(float, t); }
    if (ctrl == 0x112) { int t = __builtin_amdgcn_update_dpp(0, __builtin_bit_cast(int, f), 0x112, 0xf, 0xf, true); return f + __builtin_bit_cast(float, t); }
    if (ctrl == 0x114) { int t = __builtin_amdgcn_update_dpp(0, __builtin_bit_cast(int, f), 0x114, 0xf, 0xf, true); return f + __builtin_bit_cast(float, t); }
    if (ctrl == 0x118) { int t = __builtin_amdgcn_update_dpp(0, __builtin_bit_cast(int, f), 0x118, 0xf, 0xf, true); return f + __builtin_bit_cast(float, t); }
    if (ctrl == 0x142 && rmask == 0xa) { int t = __builtin_amdgcn_update_dpp(0, __builtin_bit_cast(int, f), 0x142, 0xa, 0xf, true); return f + __builtin_bit_cast(float, t); }
    { int t = __builtin_amdgcn_update_dpp(0, __builtin_bit_cast(int, f), 0x143, 0xc, 0xf, true); return f + __builtin_bit_cast(float, t); }
}

// full 64-lane sum, result broadcast to all lanes
static __device__ __forceinline__ float wave_sum64(float f) {
    f = dpp_add_step(f, 0x111, 0xf);
    f = dpp_add_step(f, 0x112, 0xf);
    f = dpp_add_step(f, 0x114, 0xf);
    f = dpp_add_step(f, 0x118, 0xf);
    f = dpp_add_step(f, 0x142, 0xa);   // row_bcast15 -> rows 1,3 ; lane31/63 = half sums
    f = dpp_add_step(f, 0x143, 0xc);   // row_bcast31 -> rows 2,3 ; lane63 = total
    return __builtin_bit_cast(float, __builtin_amdgcn_readlane(__builtin_bit_cast(int, f), 63));
}

// per-32-lane-half sum, each lane gets its half's total
static __device__ __forceinline__ float half_sum32(float f, int half) {
    f = dpp_add_step(f, 0x111, 0xf);
    f = dpp_add_step(f, 0x112, 0xf);
    f = dpp_add_step(f, 0x114, 0xf);
    f = dpp_add_step(f, 0x118, 0xf);
    f = dpp_add_step(f, 0x142, 0xa);   // lane31 = lanes0..31 sum, lane63 = lanes32..63 sum
    float s0 = __builtin_bit_cast(float, __builtin_amdgcn_readlane(__builtin_bit_cast(int, f), 31));
    float s1 = __builtin_bit_cast(float, __builtin_amdgcn_readlane(__builtin_bit_cast(int, f), 63));
    return half ? s1 : s0;
}

static __device__ __forceinline__ float readlane_f(float v, int lane) {
    return __builtin_bit_cast(float, __builtin_amdgcn_readlane(__builtin_bit_cast(int, v), lane));
}

static __device__ __forceinline__ bf16x8 ld_lds8(const __bf16* p) {
    union { bf16x8 v; unsigned long long q[2]; } u;
    u.q[0] = *(const unsigned long long*)(p);
    u.q[1] = *(const unsigned long long*)(p + 4);
    return u.v;
}

// ---------------- mask dtype detection (int32 vs packed int8 bool) ----------------
__global__ __launch_bounds__(256) void k_detect_mask(const int* __restrict__ mask_w,
                                                     int* __restrict__ flag) {
    __shared__ int bad;
    if (threadIdx.x == 0) bad = 0;
    __syncthreads();
    int local = 0;
    for (int i = threadIdx.x; i < 16384; i += 256) {
        int v = mask_w[i];
        if (v != 0 && v != 1) local = 1;
    }
    if (local) atomicOr(&bad, 1);
    __syncthreads();
    if (threadIdx.x == 0) *flag = bad;   // 1 => data is packed int8 bools
}

static __device__ __forceinline__ int read_mask(const int* mw, int is_i8, int idx) {
    if (is_i8) return (int)((const unsigned char*)mw)[idx];
    return mw[idx];
}

// ---------------- Wo -> bf16 hi/lo, layout [o][144] (K padded 129->144 with zeros) ----------------
__global__ __launch_bounds__(256) void k_prep_wo(const float* __restrict__ Wo,
                                                 __bf16* __restrict__ Woh,
                                                 __bf16* __restrict__ Wol) {
    int idx = blockIdx.x * 256 + threadIdx.x;
    if (idx >= 128 * 144) return;
    int o = idx / 144, d = idx - o * 144;
    float v = (d < DP1) ? Wo[o * DP1 + d] : 0.f;
    __bf16 h = (__bf16)v;
    Woh[idx] = h;
    Wol[idx] = (__bf16)(v - (float)h);
}

// ---------------- embedding + Lorentz expmap0 -> bf16 hi/lo rows + comp0/comp128 f32 ----------------
__global__ __launch_bounds__(256) void k_prep(const int* __restrict__ tok,
                                              const float* __restrict__ emb,
                                              __bf16* __restrict__ Xh, __bf16* __restrict__ Xl,
                                              float* __restrict__ X0g, float* __restrict__ X128g) {
    __shared__ float Xf[64][132];
    const int t = threadIdx.x, w = t >> 6, l = t & 63;
    const int base = blockIdx.x * 64;
    for (int it = 0; it < 16; ++it) {
        const int tk = w * 16 + it;
        const int id = tok[base + tk];
        const float2 v = ((const float2*)(emb + (size_t)id * D_))[l];
        float s = wave_sum64(v.x * v.x + v.y * v.y);
        float nv = fmaxf(sqrtf(s), 1e-7f);
        float a = SCf * nv;
        float a2 = a * a;
        float shc, ch;
        if (a < 0.5f) {  // wave-uniform branch; series exact to ~1e-11 here
            shc = 1.f + a2 * (1.f/6.f) * (1.f + a2 * (1.f/20.f) * (1.f + a2 * (1.f/42.f)));
            ch  = 1.f + a2 * 0.5f * (1.f + a2 * (1.f/12.f) * (1.f + a2 * (1.f/30.f)));
        } else {
            float ea = __expf(a), ei = 1.f / ea;
            ch = 0.5f * (ea + ei);
            shc = 0.5f * (ea - ei) / a;
        }
        Xf[tk][1 + 2 * l] = v.x * shc;   // spatial = v * sinh(a)/a
        Xf[tk][2 + 2 * l] = v.y * shc;
        if (l == 0) Xf[tk][0] = ch / SCf;
    }
    __syncthreads();
    // row-major bf16 hi/lo of comps 0..127
    const int tk2 = t >> 2, dg = (t & 3) * 32;
    for (int i = 0; i < 32; i += 8) {
        bf16x8 hv, lv;
        #pragma unroll
        for (int j = 0; j < 8; ++j) {
            float f = Xf[tk2][dg + i + j];
            __bf16 h = (__bf16)f;
            hv[j] = h;
            lv[j] = (__bf16)(f - (float)h);
        }
        *(bf16x8*)(Xh + (size_t)(base + tk2) * D_ + dg + i) = hv;
        *(bf16x8*)(Xl + (size_t)(base + tk2) * D_ + dg + i) = lv;
    }
    if (t < 64) {
        X0g[base + t]   = Xf[t][0];
        X128g[base + t] = Xf[t][D_];
    }
}

// ---------------- fused MFMA attention: scores + exp + centroid + renorm + projection + expmap ----------------
__global__ __launch_bounds__(256, 2) void k_attn(
        const __bf16* __restrict__ Xh, const __bf16* __restrict__ Xl,
        const float* __restrict__ X0g, const float* __restrict__ X128g,
        const int* __restrict__ mask, const int* __restrict__ mflag,
        const __bf16* __restrict__ Woh, const __bf16* __restrict__ Wol,
        const float* __restrict__ bo,
        float* __restrict__ Y, float* __restrict__ Y2) {
    extern __shared__ char smem[];
    // main-loop carve (53760 B): Krow [2][32][132] | XT [2][128][36] | Pb [4][2][32][36]
    __bf16* Krow = (__bf16*)smem;                   // 16896 B
    __bf16* XTb  = (__bf16*)(smem + 16896);         // 18432 B
    __bf16* Pb   = (__bf16*)(smem + 35328);         // 18432 B
    __shared__ float K0s[KT];
    __shared__ float K128s[KT];
    __shared__ int   Ms[KT];

    const int b    = blockIdx.y;
    const int qb   = blockIdx.x * QB;
    const int t    = threadIdx.x;
    const int w    = t >> 6;
    const int l    = t & 63;
    const int l31  = l & 31;
    const int half = l >> 5;
    const int is8  = *mflag;

    // ---- Q fragments (A operand): A[m=lane&31][k=(lane>>5)*8+j], hi/lo, 8 k-steps over comps 0..127 ----
    const size_t qrow = (size_t)(b * N_ + qb + w * 32 + l31);
    bf16x8 qfh[8], qfl[8];
    #pragma unroll
    for (int ks = 0; ks < 8; ++ks) {
        qfh[ks] = *(const bf16x8*)(Xh + qrow * D_ + ks * 16 + half * 8);
        qfl[ks] = *(const bf16x8*)(Xl + qrow * D_ + ks * 16 + half * 8);
    }
    // per-C-row query scalars (row = (r&3)+8*(r>>2)+4*half)
    float q0[16], q128[16];
    #pragma unroll
    for (int r = 0; r < 16; ++r) {
        const int qr = (r & 3) + 8 * (r >> 2) + 4 * half;
        q0[r]   = X0g[b * N_ + qb + w * 32 + qr];
        q128[r] = X128g[b * N_ + qb + w * 32 + qr];
    }

    f32x16 accM[4] = {};      // centroid accumulators (unnormalized): comps 32*nt + l31, rows = queries
    float  mu128p[16] = {};   // per-lane partials of comp 128 (lane = key)

    for (int kt = 0; kt < N_ / KT; ++kt) {
        __syncthreads();
        // ---- stage key tile: Krow (key-major) + XT (comp-major transpose), hi/lo ----
        {
            const int key = t >> 3, ck = t & 7;
            const size_t krow = (size_t)(b * N_ + kt * KT + key);
            #pragma unroll
            for (int ch = 0; ch < 2; ++ch) {
                const int c0 = ck * 8 + 64 * ch;
                bf16x8 vh = *(const bf16x8*)(Xh + krow * D_ + c0);
                bf16x8 vl = *(const bf16x8*)(Xl + krow * D_ + c0);
                union { bf16x8 v; unsigned long long q[2]; } uh, ul;
                uh.v = vh; ul.v = vl;
                *(unsigned long long*)(Krow + key * 132 + c0)            = uh.q[0];
                *(unsigned long long*)(Krow + key * 132 + c0 + 4)        = uh.q[1];
                *(unsigned long long*)(Krow + 4224 + key * 132 + c0)     = ul.q[0];
                *(unsigned long long*)(Krow + 4224 + key * 132 + c0 + 4) = ul.q[1];
                #pragma unroll
                for (int j = 0; j < 8; ++j) {
                    XTb[(c0 + j) * 36 + key]        = vh[j];
                    XTb[4608 + (c0 + j) * 36 + key] = vl[j];
                }
            }
            if (t < KT) {
                K0s[t]   = X0g[b * N_ + kt * KT + t];
                K128s[t] = X128g[b * N_ + kt * KT + t];
                Ms[t]    = read_mask(mask, is8, b * N_ + kt * KT + t);
            }
        }
        __syncthreads();

        // ---- phase A: S = Q . K  (3-product bf16 split), C: col=key, row=query ----
        f32x16 accS = {};
        #pragma unroll
        for (int ks = 0; ks < 8; ++ks) {
            bf16x8 bh = ld_lds8(Krow + l31 * 132 + ks * 16 + half * 8);
            bf16x8 bl = ld_lds8(Krow + 4224 + l31 * 132 + ks * 16 + half * 8);
            accS = MFMA(qfh[ks], bh, accS);
            accS = MFMA(qfh[ks], bl, accS);
            accS = MFMA(qfl[ks], bh, accS);
        }
        const float k0v = K0s[l31], k128v = K128s[l31];
        const int   mv  = Ms[l31];
        #pragma unroll
        for (int r = 0; r < 16; ++r) {
            // score = (2*q0*k0 - dot_{0..127} - q128*k128) / sqrt(129)  (Lorentz sign trick)
            float sc = (2.f * q0[r] * k0v - accS[r] - q128[r] * k128v) * SCALE;
            float e  = mv ? __expf(sc) : 0.f;       // unnormalized softmax weight (scale cancels in renorm)
            mu128p[r] += e * k128v;
            __bf16 eh = (__bf16)e;
            __bf16 el = (__bf16)(e - (float)eh);
            const int qr = (r & 3) + 8 * (r >> 2) + 4 * half;
            Pb[(w * 2 + 0) * 1152 + qr * 36 + l31] = eh;
            Pb[(w * 2 + 1) * 1152 + qr * 36 + l31] = el;
        }

        // ---- phase B: mu += P . X  (A = P [q][key], B = XT [key][comp]) ----
        #pragma unroll
        for (int ks = 0; ks < 2; ++ks) {
            bf16x8 ah = ld_lds8(Pb + (w * 2 + 0) * 1152 + l31 * 36 + ks * 16 + half * 8);
            bf16x8 al = ld_lds8(Pb + (w * 2 + 1) * 1152 + l31 * 36 + ks * 16 + half * 8);
            #pragma unroll
            for (int nt = 0; nt < 4; ++nt) {
                bf16x8 bh = ld_lds8(XTb + (nt * 32 + l31) * 36 + ks * 16 + half * 8);
                bf16x8 bl = ld_lds8(XTb + 4608 + (nt * 32 + l31) * 36 + ks * 16 + half * 8);
                accM[nt] = MFMA(ah, bh, accM[nt]);
                accM[nt] = MFMA(ah, bl, accM[nt]);
                accM[nt] = MFMA(al, bh, accM[nt]);
            }
        }
    }

    // ---- Lorentz renormalization (scale-invariant: no lsum needed) ----
    #pragma unroll
    for (int r = 0; r < 16; ++r) mu128p[r] = half_sum32(mu128p[r], half);
    float rno[16];
    #pragma unroll
    for (int r = 0; r < 16; ++r) {
        float p = 0.f;
        #pragma unroll
        for (int nt = 0; nt < 4; ++nt) p += accM[nt][r] * accM[nt][r];
        if (l31 == 0) p -= 2.f * accM[0][r] * accM[0][r];   // comp 0 carries Lorentz minus sign
        p = half_sum32(p, half);
        float negI = -(p + mu128p[r] * mu128p[r]);          // = -<mu,mu>_L > 0
        negI = fmaxf(negI, 1e-7f);
        rno[r] = 1.f / (SCf * sqrtf(negI));
    }
    #pragma unroll
    for (int nt = 0; nt < 4; ++nt)
        #pragma unroll
        for (int r = 0; r < 16; ++r) accM[nt][r] *= rno[r];
    #pragma unroll
    for (int r = 0; r < 16; ++r) mu128p[r] *= rno[r];

    // ---- projection u = mu . Wo^T + bo via MFMA (mu through LDS as A-operand, hi then lo pass) ----
    __syncthreads();   // everyone done with Krow/XT/Pb; alias as MuA
    __bf16* MuA = (__bf16*)smem + w * (32 * 148);   // per-wave [32][148], K padded to 144
    // pass 1: hi
    #pragma unroll
    for (int r = 0; r < 16; ++r) {
        const int qr = (r & 3) + 8 * (r >> 2) + 4 * half;
        #pragma unroll
        for (int nt = 0; nt < 4; ++nt)
            MuA[qr * 148 + nt * 32 + l31] = (__bf16)accM[nt][r];
        if (l31 == 0) MuA[qr * 148 + 128] = (__bf16)mu128p[r];
        if (l31 >= 1 && l31 <= 15) MuA[qr * 148 + 128 + l31] = (__bf16)0.f;  // zero pad 129..143
    }
    bf16x8 Ah[9];
    #pragma unroll
    for (int ks = 0; ks < 9; ++ks) Ah[ks] = ld_lds8(MuA + l31 * 148 + ks * 16 + half * 8);
    // pass 2: lo (overwrite; zero cols stay zero)
    #pragma unroll
    for (int r = 0; r < 16; ++r) {
        const int qr = (r & 3) + 8 * (r >> 2) + 4 * half;
        #pragma unroll
        for (int nt = 0; nt < 4; ++nt) {
            float m = accM[nt][r];
            MuA[qr * 148 + nt * 32 + l31] = (__bf16)(m - (float)(__bf16)m);
        }
        if (l31 == 0) {
            float m = mu128p[r];
            MuA[qr * 148 + 128] = (__bf16)(m - (float)(__bf16)m);
        }
    }
    bf16x8 Al[9];
    #pragma unroll
    for (int ks = 0; ks < 9; ++ks) Al[ks] = ld_lds8(MuA + l31 * 148 + ks * 16 + half * 8);

    f32x16 accU[4] = {};
    #pragma unroll
    for (int ks = 0; ks < 9; ++ks) {
        #pragma unroll
        for (int nt = 0; nt < 4; ++nt) {
            bf16x8 bh = *(const bf16x8*)(Woh + (size_t)(nt * 32 + l31) * 144 + ks * 16 + half * 8);
            bf16x8 bl = *(const bf16x8*)(Wol + (size_t)(nt * 32 + l31) * 144 + ks * 16 + half * 8);
            accU[nt] = MFMA(Ah[ks], bh, accU[nt]);
            accU[nt] = MFMA(Ah[ks], bl, accU[nt]);
            accU[nt] = MFMA(Al[ks], bh, accU[nt]);
        }
    }

    // ---- bias + Poincare expmap0 + store ----
    float bov[4];
    #pragma unroll
    for (int nt = 0; nt < 4; ++nt) bov[nt] = bo[nt * 32 + l31];
    #pragma unroll
    for (int r = 0; r < 16; ++r) {
        float p = 0.f;
        #pragma unroll
        for (int nt = 0; nt < 4; ++nt) {
            float uv = accU[nt][r] + bov[nt];
            accU[nt][r] = uv;
            p += uv * uv;
        }
        float nn = half_sum32(p, half);
        float nu = fmaxf(sqrtf(nn), 1e-7f);
        float aa = SCf * nu;
        float cf = tanhf(aa) / aa;
        const int qr = (r & 3) + 8 * (r >> 2) + 4 * half;
        const size_t row = (size_t)(b * N_ + qb + w * 32 + qr);
        #pragma unroll
        for (int nt = 0; nt < 4; ++nt)
            Y[row * D_ + nt * 32 + l31] = accU[nt][r] * cf;
        if (l31 == 0) Y2[row] = nn * cf * cf;
    }
}

// ---------------- sequential Mobius fold (scale-folded recurrence) + scalarmul + logmap + MLR head ----------------
__global__ __launch_bounds__(64) void k_pool(const float* __restrict__ Y,
                                             const float* __restrict__ Y2,
                                             const int* __restrict__ mask,
                                             const int* __restrict__ mflag,
                                             const float* __restrict__ Wf,
                                             const float* __restrict__ bf_,
                                             float* __restrict__ out) {
    __shared__ double vb[D_];
    const int b = blockIdx.x, l = threadIdx.x;
    const int is8 = *mflag;
    const double c = 0.1;
    const double SCd = 0.31622776601683794;

    // acc = s * accU ; x2 = |acc|^2 ; u2 = |accU|^2 (all propagated analytically)
    float u0 = 0.f, u1 = 0.f;
    double s = 1.0, x2 = 0.0, u2 = 0.0;
    int cnt = 0;
    for (int i = 0; i < N_; ++i) {
        const float2 yv = *(const float2*)(Y + (size_t)(b * N_ + i) * D_ + 2 * l);
        const float py2f = Y2[b * N_ + i];
        const int m = read_mask(mask, is8, b * N_ + i);
        float red = wave_sum64(fmaf(u0, yv.x, u1 * yv.y));   // <accU, y>
        if (m) {   // wave-uniform
            const double puy = (double)red;
            const double py2 = (double)py2f;
            const double pxy = s * puy;
            const double A   = 1.0 + 2.0 * c * pxy + c * py2;
            const double Bc  = 1.0 - c * x2;
            double den = A - c * py2 * Bc;        // == 1 + 2c*pxy + c^2*x2*py2
            if (den < 1e-12) den = 1e-12;
            const double inv = 1.0 / den;
            const float Asf = (float)(A * s);
            const float Bcf = (float)Bc;
            u0 = fmaf(Asf, u0, Bcf * yv.x);
            u1 = fmaf(Asf, u1, Bcf * yv.y);
            const double Ad = (double)Asf, Bd = (double)Bcf;
            u2 = Ad * Ad * u2 + 2.0 * Ad * Bd * puy + Bd * Bd * py2;
            x2 = inv * inv * u2;
            s  = inv;
            ++cnt;
        }
    }

    double a0 = s * (double)u0, a1 = s * (double)u1;
    double n2 = fmax(x2, 0.0);
    double n = sqrt(n2);
    double tt = SCd * n;
    tt = fmin(fmax(tt, 1e-7), 1.0 - 1e-6);
    int cm = cnt > 0 ? cnt : 1;
    float rf = (float)(1.0 / (double)cm);        // ref casts r to float32
    double r = (double)rf;
    double dv = fmax(SCd * n, 1e-7);
    double f = tanh(r * atanh(tt)) / dv;
    double p0 = a0 * f, p1 = a1 * f;
    double q2;
    if (cnt == 0) {                              // fallback: first token's y
        float2 y0v = *(const float2*)(Y + (size_t)(b * N_) * D_ + 2 * l);
        p0 = y0v.x; p1 = y0v.y;
        q2 = (double)Y2[b * N_];
    } else {
        q2 = f * f * n2;
    }
    double npn = fmax(sqrt(q2), 1e-7);
    double t2 = fmin(fmax(SCd * npn, 1e-7), 1.0 - 1e-6);
    double f2 = atanh(t2) / (SCd * npn);
    vb[2 * l]     = p0 * f2;
    vb[2 * l + 1] = p1 * f2;
    __syncthreads();

    if (l < NC_) {
        double o = (double)bf_[l];
        for (int d = 0; d < D_; ++d) o += vb[d] * (double)Wf[l * D_ + d];
        out[b * NC_ + l] = (float)o;
    }
}

extern "C" void kernel_launch(void* const* d_in, const int* in_sizes, int n_in,
                              void* d_out, int out_size, void* d_ws, size_t ws_size,
                              hipStream_t stream) {
    const int*   tok  = (const int*)d_in[0];
    const int*   mask = (const int*)d_in[1];
    const float* emb  = (const float*)d_in[2];
    const float* Wo   = (const float*)d_in[3];
    const float* bo   = (const float*)d_in[4];
    const float* Wf   = (const float*)d_in[5];
    const float* bf_  = (const float*)d_in[6];
    float* out = (float*)d_out;

    char* wsb = (char*)d_ws;
    __bf16* Xh   = (__bf16*)wsb;                              // 16,777,216 B
    __bf16* Xl   = (__bf16*)(wsb + 16777216);                 // 16,777,216 B
    float*  X0g  = (float*)(wsb + 33554432);                  //    262,144 B
    float*  X128g= (float*)(wsb + 33816576);                  //    262,144 B
    __bf16* Woh  = (__bf16*)(wsb + 34078720);                 //     36,864 B
    __bf16* Wol  = (__bf16*)(wsb + 34115584);                 //     36,864 B
    float*  Y    = (float*)(wsb + 34152448);                  // 33,554,432 B
    float*  Y2   = (float*)(wsb + 67706880);                  //    262,144 B
    int*    flag = (int*)(wsb + 67969024);                    // total ~67.97 MB

    k_detect_mask<<<dim3(1), dim3(256), 0, stream>>>(mask, flag);
    k_prep_wo<<<dim3(72), dim3(256), 0, stream>>>(Wo, Woh, Wol);
    k_prep<<<dim3(B_ * N_ / 64), dim3(256), 0, stream>>>(tok, emb, Xh, Xl, X0g, X128g);
    k_attn<<<dim3(N_ / QB, B_), dim3(256), 53760, stream>>>(Xh, Xl, X0g, X128g, mask, flag,
                                                            Woh, Wol, bo, Y, Y2);
    k_pool<<<dim3(B_), dim3(64), 0, stream>>>(Y, Y2, mask, flag, Wf, bf_, out);
}

// Round 4
// 474.526 us; speedup vs baseline: 12.8010x; 1.4102x over previous
//
#include <hip/hip_runtime.h>
#include <math.h>

#define B_    64
#define N_    1024
#define D_    128
#define DP1   129
#define NC_   10
#define QB    128     // queries per block (4 waves x 32)
#define KT    32      // key tile
#define SCf   0.31622776601683794f
#define SCALE 0.08804509063256238f   // 1/sqrt(129)

typedef __bf16 bf16x8 __attribute__((ext_vector_type(8)));
typedef float  f32x16 __attribute__((ext_vector_type(16)));

#define MFMA(a, b, c) __builtin_amdgcn_mfma_f32_32x32x16_bf16((a), (b), (c), 0, 0, 0)

static __device__ __forceinline__ float dpp_add_step(float f, int ctrl, int rmask) {
    if (ctrl == 0x111) { int t = __builtin_amdgcn_update_dpp(0, __builtin_bit_cast(int, f), 0x111, 0xf, 0xf, true); return f + __builtin_bit_cast(float, t); }
    if (ctrl == 0x112) { int t = __builtin_amdgcn_update_dpp(0, __builtin_bit_cast(int, f), 0x112, 0xf, 0xf, true); return f + __builtin_bit_cast(float, t); }
    if (ctrl == 0x114) { int t = __builtin_amdgcn_update_dpp(0, __builtin_bit_cast(int, f), 0x114, 0xf, 0xf, true); return f + __builtin_bit_cast(float, t); }
    if (ctrl == 0x118) { int t = __builtin_amdgcn_update_dpp(0, __builtin_bit_cast(int, f), 0x118, 0xf, 0xf, true); return f + __builtin_bit_cast(float, t); }
    if (ctrl == 0x142 && rmask == 0xa) { int t = __builtin_amdgcn_update_dpp(0, __builtin_bit_cast(int, f), 0x142, 0xa, 0xf, true); return f + __builtin_bit_cast(float, t); }
    { int t = __builtin_amdgcn_update_dpp(0, __builtin_bit_cast(int, f), 0x143, 0xc, 0xf, true); return f + __builtin_bit_cast(float, t); }
}

// full 64-lane sum, result broadcast to all lanes
static __device__ __forceinline__ float wave_sum64(float f) {
    f = dpp_add_step(f, 0x111, 0xf);
    f = dpp_add_step(f, 0x112, 0xf);
    f = dpp_add_step(f, 0x114, 0xf);
    f = dpp_add_step(f, 0x118, 0xf);
    f = dpp_add_step(f, 0x142, 0xa);   // row_bcast15 -> rows 1,3 ; lane31/63 = half sums
    f = dpp_add_step(f, 0x143, 0xc);   // row_bcast31 -> rows 2,3 ; lane63 = total
    return __builtin_bit_cast(float, __builtin_amdgcn_readlane(__builtin_bit_cast(int, f), 63));
}

// per-32-lane-half sum, each lane gets its half's total
static __device__ __forceinline__ float half_sum32(float f, int half) {
    f = dpp_add_step(f, 0x111, 0xf);
    f = dpp_add_step(f, 0x112, 0xf);
    f = dpp_add_step(f, 0x114, 0xf);
    f = dpp_add_step(f, 0x118, 0xf);
    f = dpp_add_step(f, 0x142, 0xa);
    float s0 = __builtin_bit_cast(float, __builtin_amdgcn_readlane(__builtin_bit_cast(int, f), 31));
    float s1 = __builtin_bit_cast(float, __builtin_amdgcn_readlane(__builtin_bit_cast(int, f), 63));
    return half ? s1 : s0;
}

static __device__ __forceinline__ bf16x8 ld_lds8(const __bf16* p) {
    union { bf16x8 v; unsigned long long q[2]; } u;
    u.q[0] = *(const unsigned long long*)(p);
    u.q[1] = *(const unsigned long long*)(p + 4);
    return u.v;
}

// ---------------- mask dtype detection (int32 vs packed int8 bool) ----------------
__global__ __launch_bounds__(256) void k_detect_mask(const int* __restrict__ mask_w,
                                                     int* __restrict__ flag) {
    __shared__ int bad;
    if (threadIdx.x == 0) bad = 0;
    __syncthreads();
    int local = 0;
    for (int i = threadIdx.x; i < 16384; i += 256) {
        int v = mask_w[i];
        if (v != 0 && v != 1) local = 1;
    }
    if (local) atomicOr(&bad, 1);
    __syncthreads();
    if (threadIdx.x == 0) *flag = bad;   // 1 => data is packed int8 bools
}

static __device__ __forceinline__ int read_mask(const int* mw, int is_i8, int idx) {
    if (is_i8) return (int)((const unsigned char*)mw)[idx];
    return mw[idx];
}

// ---------------- Wo -> bf16 hi/lo, layout [o][144] (K padded 129->144 with zeros) ----------------
__global__ __launch_bounds__(256) void k_prep_wo(const float* __restrict__ Wo,
                                                 __bf16* __restrict__ Woh,
                                                 __bf16* __restrict__ Wol) {
    int idx = blockIdx.x * 256 + threadIdx.x;
    if (idx >= 128 * 144) return;
    int o = idx / 144, d = idx - o * 144;
    float v = (d < DP1) ? Wo[o * DP1 + d] : 0.f;
    __bf16 h = (__bf16)v;
    Woh[idx] = h;
    Wol[idx] = (__bf16)(v - (float)h);
}

// ---------------- embedding + Lorentz expmap0 -> bf16 hi/lo rows + comp0/comp128 f32 ----------------
__global__ __launch_bounds__(256) void k_prep(const int* __restrict__ tok,
                                              const float* __restrict__ emb,
                                              __bf16* __restrict__ Xh, __bf16* __restrict__ Xl,
                                              float* __restrict__ X0g, float* __restrict__ X128g) {
    __shared__ float Xf[64][132];
    const int t = threadIdx.x, w = t >> 6, l = t & 63;
    const int base = blockIdx.x * 64;
    for (int it = 0; it < 16; ++it) {
        const int tk = w * 16 + it;
        const int id = tok[base + tk];
        const float2 v = ((const float2*)(emb + (size_t)id * D_))[l];
        float s = wave_sum64(v.x * v.x + v.y * v.y);
        float nv = fmaxf(sqrtf(s), 1e-7f);
        float a = SCf * nv;
        float a2 = a * a;
        float shc, ch;
        if (a < 0.5f) {
            shc = 1.f + a2 * (1.f/6.f) * (1.f + a2 * (1.f/20.f) * (1.f + a2 * (1.f/42.f)));
            ch  = 1.f + a2 * 0.5f * (1.f + a2 * (1.f/12.f) * (1.f + a2 * (1.f/30.f)));
        } else {
            float ea = __expf(a), ei = 1.f / ea;
            ch = 0.5f * (ea + ei);
            shc = 0.5f * (ea - ei) / a;
        }
        Xf[tk][1 + 2 * l] = v.x * shc;
        Xf[tk][2 + 2 * l] = v.y * shc;
        if (l == 0) Xf[tk][0] = ch / SCf;
    }
    __syncthreads();
    const int tk2 = t >> 2, dg = (t & 3) * 32;
    for (int i = 0; i < 32; i += 8) {
        bf16x8 hv, lv;
        #pragma unroll
        for (int j = 0; j < 8; ++j) {
            float f = Xf[tk2][dg + i + j];
            __bf16 h = (__bf16)f;
            hv[j] = h;
            lv[j] = (__bf16)(f - (float)h);
        }
        *(bf16x8*)(Xh + (size_t)(base + tk2) * D_ + dg + i) = hv;
        *(bf16x8*)(Xl + (size_t)(base + tk2) * D_ + dg + i) = lv;
    }
    if (t < 64) {
        X0g[base + t]   = Xf[t][0];
        X128g[base + t] = Xf[t][D_];
    }
}

// ---------------- fused MFMA attention: scores + exp + centroid + renorm + projection + expmap ----------------
__global__ __launch_bounds__(256, 2) void k_attn(
        const __bf16* __restrict__ Xh, const __bf16* __restrict__ Xl,
        const float* __restrict__ X0g, const float* __restrict__ X128g,
        const int* __restrict__ mask, const int* __restrict__ mflag,
        const __bf16* __restrict__ Woh, const __bf16* __restrict__ Wol,
        const float* __restrict__ bo,
        float* __restrict__ Y, float* __restrict__ Y2) {
    extern __shared__ char smem[];
    __bf16* Krow = (__bf16*)smem;                   // 16896 B
    __bf16* XTb  = (__bf16*)(smem + 16896);         // 18432 B
    __bf16* Pb   = (__bf16*)(smem + 35328);         // 18432 B
    __shared__ float K0s[KT];
    __shared__ float K128s[KT];
    __shared__ int   Ms[KT];

    const int b    = blockIdx.y;
    const int qb   = blockIdx.x * QB;
    const int t    = threadIdx.x;
    const int w    = t >> 6;
    const int l    = t & 63;
    const int l31  = l & 31;
    const int half = l >> 5;
    const int is8  = *mflag;

    const size_t qrow = (size_t)(b * N_ + qb + w * 32 + l31);
    bf16x8 qfh[8], qfl[8];
    #pragma unroll
    for (int ks = 0; ks < 8; ++ks) {
        qfh[ks] = *(const bf16x8*)(Xh + qrow * D_ + ks * 16 + half * 8);
        qfl[ks] = *(const bf16x8*)(Xl + qrow * D_ + ks * 16 + half * 8);
    }
    float q0[16], q128[16];
    #pragma unroll
    for (int r = 0; r < 16; ++r) {
        const int qr = (r & 3) + 8 * (r >> 2) + 4 * half;
        q0[r]   = X0g[b * N_ + qb + w * 32 + qr];
        q128[r] = X128g[b * N_ + qb + w * 32 + qr];
    }

    f32x16 accM[4] = {};
    float  mu128p[16] = {};

    for (int kt = 0; kt < N_ / KT; ++kt) {
        __syncthreads();
        {
            const int key = t >> 3, ck = t & 7;
            const size_t krow = (size_t)(b * N_ + kt * KT + key);
            #pragma unroll
            for (int ch = 0; ch < 2; ++ch) {
                const int c0 = ck * 8 + 64 * ch;
                bf16x8 vh = *(const bf16x8*)(Xh + krow * D_ + c0);
                bf16x8 vl = *(const bf16x8*)(Xl + krow * D_ + c0);
                union { bf16x8 v; unsigned long long q[2]; } uh, ul;
                uh.v = vh; ul.v = vl;
                *(unsigned long long*)(Krow + key * 132 + c0)            = uh.q[0];
                *(unsigned long long*)(Krow + key * 132 + c0 + 4)        = uh.q[1];
                *(unsigned long long*)(Krow + 4224 + key * 132 + c0)     = ul.q[0];
                *(unsigned long long*)(Krow + 4224 + key * 132 + c0 + 4) = ul.q[1];
                #pragma unroll
                for (int j = 0; j < 8; ++j) {
                    XTb[(c0 + j) * 36 + key]        = vh[j];
                    XTb[4608 + (c0 + j) * 36 + key] = vl[j];
                }
            }
            if (t < KT) {
                K0s[t]   = X0g[b * N_ + kt * KT + t];
                K128s[t] = X128g[b * N_ + kt * KT + t];
                Ms[t]    = read_mask(mask, is8, b * N_ + kt * KT + t);
            }
        }
        __syncthreads();

        f32x16 accS = {};
        #pragma unroll
        for (int ks = 0; ks < 8; ++ks) {
            bf16x8 bh = ld_lds8(Krow + l31 * 132 + ks * 16 + half * 8);
            bf16x8 bl = ld_lds8(Krow + 4224 + l31 * 132 + ks * 16 + half * 8);
            accS = MFMA(qfh[ks], bh, accS);
            accS = MFMA(qfh[ks], bl, accS);
            accS = MFMA(qfl[ks], bh, accS);
        }
        const float k0v = K0s[l31], k128v = K128s[l31];
        const int   mv  = Ms[l31];
        #pragma unroll
        for (int r = 0; r < 16; ++r) {
            float sc = (2.f * q0[r] * k0v - accS[r] - q128[r] * k128v) * SCALE;
            float e  = mv ? __expf(sc) : 0.f;
            mu128p[r] += e * k128v;
            __bf16 eh = (__bf16)e;
            __bf16 el = (__bf16)(e - (float)eh);
            const int qr = (r & 3) + 8 * (r >> 2) + 4 * half;
            Pb[(w * 2 + 0) * 1152 + qr * 36 + l31] = eh;
            Pb[(w * 2 + 1) * 1152 + qr * 36 + l31] = el;
        }

        #pragma unroll
        for (int ks = 0; ks < 2; ++ks) {
            bf16x8 ah = ld_lds8(Pb + (w * 2 + 0) * 1152 + l31 * 36 + ks * 16 + half * 8);
            bf16x8 al = ld_lds8(Pb + (w * 2 + 1) * 1152 + l31 * 36 + ks * 16 + half * 8);
            #pragma unroll
            for (int nt = 0; nt < 4; ++nt) {
                bf16x8 bh = ld_lds8(XTb + (nt * 32 + l31) * 36 + ks * 16 + half * 8);
                bf16x8 bl = ld_lds8(XTb + 4608 + (nt * 32 + l31) * 36 + ks * 16 + half * 8);
                accM[nt] = MFMA(ah, bh, accM[nt]);
                accM[nt] = MFMA(ah, bl, accM[nt]);
                accM[nt] = MFMA(al, bh, accM[nt]);
            }
        }
    }

    #pragma unroll
    for (int r = 0; r < 16; ++r) mu128p[r] = half_sum32(mu128p[r], half);
    float rno[16];
    #pragma unroll
    for (int r = 0; r < 16; ++r) {
        float p = 0.f;
        #pragma unroll
        for (int nt = 0; nt < 4; ++nt) p += accM[nt][r] * accM[nt][r];
        if (l31 == 0) p -= 2.f * accM[0][r] * accM[0][r];
        p = half_sum32(p, half);
        float negI = -(p + mu128p[r] * mu128p[r]);
        negI = fmaxf(negI, 1e-7f);
        rno[r] = 1.f / (SCf * sqrtf(negI));
    }
    #pragma unroll
    for (int nt = 0; nt < 4; ++nt)
        #pragma unroll
        for (int r = 0; r < 16; ++r) accM[nt][r] *= rno[r];
    #pragma unroll
    for (int r = 0; r < 16; ++r) mu128p[r] *= rno[r];

    __syncthreads();
    __bf16* MuA = (__bf16*)smem + w * (32 * 148);
    #pragma unroll
    for (int r = 0; r < 16; ++r) {
        const int qr = (r & 3) + 8 * (r >> 2) + 4 * half;
        #pragma unroll
        for (int nt = 0; nt < 4; ++nt)
            MuA[qr * 148 + nt * 32 + l31] = (__bf16)accM[nt][r];
        if (l31 == 0) MuA[qr * 148 + 128] = (__bf16)mu128p[r];
        if (l31 >= 1 && l31 <= 15) MuA[qr * 148 + 128 + l31] = (__bf16)0.f;
    }
    bf16x8 Ah[9];
    #pragma unroll
    for (int ks = 0; ks < 9; ++ks) Ah[ks] = ld_lds8(MuA + l31 * 148 + ks * 16 + half * 8);
    #pragma unroll
    for (int r = 0; r < 16; ++r) {
        const int qr = (r & 3) + 8 * (r >> 2) + 4 * half;
        #pragma unroll
        for (int nt = 0; nt < 4; ++nt) {
            float m = accM[nt][r];
            MuA[qr * 148 + nt * 32 + l31] = (__bf16)(m - (float)(__bf16)m);
        }
        if (l31 == 0) {
            float m = mu128p[r];
            MuA[qr * 148 + 128] = (__bf16)(m - (float)(__bf16)m);
        }
    }
    bf16x8 Al[9];
    #pragma unroll
    for (int ks = 0; ks < 9; ++ks) Al[ks] = ld_lds8(MuA + l31 * 148 + ks * 16 + half * 8);

    f32x16 accU[4] = {};
    #pragma unroll
    for (int ks = 0; ks < 9; ++ks) {
        #pragma unroll
        for (int nt = 0; nt < 4; ++nt) {
            bf16x8 bh = *(const bf16x8*)(Woh + (size_t)(nt * 32 + l31) * 144 + ks * 16 + half * 8);
            bf16x8 bl = *(const bf16x8*)(Wol + (size_t)(nt * 32 + l31) * 144 + ks * 16 + half * 8);
            accU[nt] = MFMA(Ah[ks], bh, accU[nt]);
            accU[nt] = MFMA(Ah[ks], bl, accU[nt]);
            accU[nt] = MFMA(Al[ks], bh, accU[nt]);
        }
    }

    float bov[4];
    #pragma unroll
    for (int nt = 0; nt < 4; ++nt) bov[nt] = bo[nt * 32 + l31];
    #pragma unroll
    for (int r = 0; r < 16; ++r) {
        float p = 0.f;
        #pragma unroll
        for (int nt = 0; nt < 4; ++nt) {
            float uv = accU[nt][r] + bov[nt];
            accU[nt][r] = uv;
            p += uv * uv;
        }
        float nn = half_sum32(p, half);
        float nu = fmaxf(sqrtf(nn), 1e-7f);
        float aa = SCf * nu;
        float cf = tanhf(aa) / aa;
        const int qr = (r & 3) + 8 * (r >> 2) + 4 * half;
        const size_t row = (size_t)(b * N_ + qb + w * 32 + qr);
        #pragma unroll
        for (int nt = 0; nt < 4; ++nt)
            Y[row * D_ + nt * 32 + l31] = accU[nt][r] * cf;
        if (l31 == 0) Y2[row] = nn * cf * cf;
    }
}

// ---------------- sequential Mobius fold: prefetched, branchless, chain-minimized ----------------
__global__ __launch_bounds__(64) void k_pool(const float* __restrict__ Y,
                                             const float* __restrict__ Y2,
                                             const int* __restrict__ mask,
                                             const int* __restrict__ mflag,
                                             const float* __restrict__ Wf,
                                             const float* __restrict__ bf_,
                                             float* __restrict__ out) {
    __shared__ float         py2s[N_];
    __shared__ unsigned char ms[N_];
    __shared__ double        vb[D_];
    const int b = blockIdx.x, l = threadIdx.x;
    const int is8 = *mflag;
    const double c = 0.1;
    const double SCd = 0.31622776601683794;

    // preload per-step scalars (off the recurrence path entirely)
    for (int i = l; i < N_; i += 64) {
        py2s[i] = Y2[b * N_ + i];
        ms[i]   = (unsigned char)read_mask(mask, is8, b * N_ + i);
    }
    __syncthreads();

    // lane's column of Y: row i at Yp[i*64]
    const float2* __restrict__ Yp = (const float2*)(Y + (size_t)b * N_ * D_) + l;

    constexpr int PF = 16;                 // covers ~900-cyc HBM latency at ~100 cyc/step
    float2 buf[PF];
    #pragma unroll
    for (int k = 0; k < PF; ++k) buf[k] = Yp[(size_t)k * 64];

    // acc = s * (u0,u1,...) ; x2=|acc|^2 ; u2=|u|^2 ; all f64 except u,dot
    float  u0 = 0.f, u1 = 0.f;
    double s = 1.0, x2 = 0.0, u2 = 0.0;
    double Bcur = 1.0;                     // Bc = 1 - c*x2
    double tcs  = 2.0 * c;                 // 2*c*s
    int cnt = 0;

    for (int i0 = 0; i0 < N_; i0 += PF) {
        #pragma unroll
        for (int k = 0; k < PF; ++k) {
            const int i = i0 + k;
            const float2 yv = buf[k];
            const int inx = i + PF;
            if (inx < N_) buf[k] = Yp[(size_t)inx * 64];

            const double py2   = (double)py2s[i];
            const double onepc = fma(c, py2, 1.0);       // 1 + c*py2   (off-chain)
            const double qv    = c * py2 * Bcur;         // c*py2*Bc    (off-chain)
            const bool   m     = ms[i] != 0;

            // --- critical chain: dot -> reduce -> A -> A*s -> u update ---
            const float  red = wave_sum64(fmaf(u0, yv.x, u1 * yv.y));
            const double puy = (double)red;
            const double A   = fma(tcs, puy, onepc);     // 1 + 2c*s*puy + c*py2
            const double As  = A * s;
            const float Asf = m ? (float)As : 1.0f;
            const float Bcf = m ? (float)Bcur : 0.0f;
            u0 = fmaf(Asf, u0, Bcf * yv.x);
            u1 = fmaf(Asf, u1, Bcf * yv.y);

            // --- slack path (consumed next iteration) ---
            const double Ad = (double)Asf, Bd = (double)Bcf;
            u2 = Ad * Ad * u2 + 2.0 * Ad * Bd * puy + Bd * Bd * py2;   // identity when m=0
            double den = A - qv;                         // == 1 + 2c*pxy + c^2*x2*py2
            den = fmax(den, 1e-12);
            const double inv = 1.0 / den;
            s  = m ? inv : s;
            x2 = m ? inv * inv * u2 : x2;
            Bcur = fma(-c, x2, 1.0);
            tcs  = 2.0 * c * s;
            cnt += m ? 1 : 0;
        }
    }

    double a0 = s * (double)u0, a1 = s * (double)u1;
    double n2 = fmax(x2, 0.0);
    double n = sqrt(n2);
    double tt = SCd * n;
    tt = fmin(fmax(tt, 1e-7), 1.0 - 1e-6);
    int cm = cnt > 0 ? cnt : 1;
    float rf = (float)(1.0 / (double)cm);        // ref casts r to float32
    double r = (double)rf;
    double dv = fmax(SCd * n, 1e-7);
    double f = tanh(r * atanh(tt)) / dv;
    double p0 = a0 * f, p1 = a1 * f;
    double q2;
    if (cnt == 0) {                              // fallback: first token's y
        float2 y0v = *(const float2*)(Y + (size_t)(b * N_) * D_ + 2 * l);
        p0 = y0v.x; p1 = y0v.y;
        q2 = (double)Y2[b * N_];
    } else {
        q2 = f * f * n2;
    }
    double npn = fmax(sqrt(q2), 1e-7);
    double t2 = fmin(fmax(SCd * npn, 1e-7), 1.0 - 1e-6);
    double f2 = atanh(t2) / (SCd * npn);
    vb[2 * l]     = p0 * f2;
    vb[2 * l + 1] = p1 * f2;
    __syncthreads();

    if (l < NC_) {
        double o = (double)bf_[l];
        for (int d = 0; d < D_; ++d) o += vb[d] * (double)Wf[l * D_ + d];
        out[b * NC_ + l] = (float)o;
    }
}

extern "C" void kernel_launch(void* const* d_in, const int* in_sizes, int n_in,
                              void* d_out, int out_size, void* d_ws, size_t ws_size,
                              hipStream_t stream) {
    const int*   tok  = (const int*)d_in[0];
    const int*   mask = (const int*)d_in[1];
    const float* emb  = (const float*)d_in[2];
    const float* Wo   = (const float*)d_in[3];
    const float* bo   = (const float*)d_in[4];
    const float* Wf   = (const float*)d_in[5];
    const float* bf_  = (const float*)d_in[6];
    float* out = (float*)d_out;

    char* wsb = (char*)d_ws;
    __bf16* Xh   = (__bf16*)wsb;                              // 16,777,216 B
    __bf16* Xl   = (__bf16*)(wsb + 16777216);                 // 16,777,216 B
    float*  X0g  = (float*)(wsb + 33554432);                  //    262,144 B
    float*  X128g= (float*)(wsb + 33816576);                  //    262,144 B
    __bf16* Woh  = (__bf16*)(wsb + 34078720);                 //     36,864 B
    __bf16* Wol  = (__bf16*)(wsb + 34115584);                 //     36,864 B
    float*  Y    = (float*)(wsb + 34152448);                  // 33,554,432 B
    float*  Y2   = (float*)(wsb + 67706880);                  //    262,144 B
    int*    flag = (int*)(wsb + 67969024);                    // total ~67.97 MB

    k_detect_mask<<<dim3(1), dim3(256), 0, stream>>>(mask, flag);
    k_prep_wo<<<dim3(72), dim3(256), 0, stream>>>(Wo, Woh, Wol);
    k_prep<<<dim3(B_ * N_ / 64), dim3(256), 0, stream>>>(tok, emb, Xh, Xl, X0g, X128g);
    k_attn<<<dim3(N_ / QB, B_), dim3(256), 53760, stream>>>(Xh, Xl, X0g, X128g, mask, flag,
                                                            Woh, Wol, bo, Y, Y2);
    k_pool<<<dim3(B_), dim3(64), 0, stream>>>(Y, Y2, mask, flag, Wf, bf_, out);
}

// Round 5
// 445.360 us; speedup vs baseline: 13.6393x; 1.0655x over previous
//
#include <hip/hip_runtime.h>
#include <math.h>

#define B_    64
#define N_    1024
#define D_    128
#define DP1   129
#define NC_   10
#define QB    128     // queries per block (4 waves x 32)
#define KT    32      // key tile
#define SCf   0.31622776601683794f
#define SCALE 0.08804509063256238f   // 1/sqrt(129)

typedef __bf16 bf16x8 __attribute__((ext_vector_type(8)));
typedef float  f32x16 __attribute__((ext_vector_type(16)));

#define MFMA(a, b, c) __builtin_amdgcn_mfma_f32_32x32x16_bf16((a), (b), (c), 0, 0, 0)

static __device__ __forceinline__ float dpp_add_step(float f, int ctrl, int rmask) {
    if (ctrl == 0x111) { int t = __builtin_amdgcn_update_dpp(0, __builtin_bit_cast(int, f), 0x111, 0xf, 0xf, true); return f + __builtin_bit_cast(float, t); }
    if (ctrl == 0x112) { int t = __builtin_amdgcn_update_dpp(0, __builtin_bit_cast(int, f), 0x112, 0xf, 0xf, true); return f + __builtin_bit_cast(float, t); }
    if (ctrl == 0x114) { int t = __builtin_amdgcn_update_dpp(0, __builtin_bit_cast(int, f), 0x114, 0xf, 0xf, true); return f + __builtin_bit_cast(float, t); }
    if (ctrl == 0x118) { int t = __builtin_amdgcn_update_dpp(0, __builtin_bit_cast(int, f), 0x118, 0xf, 0xf, true); return f + __builtin_bit_cast(float, t); }
    if (ctrl == 0x142 && rmask == 0xa) { int t = __builtin_amdgcn_update_dpp(0, __builtin_bit_cast(int, f), 0x142, 0xa, 0xf, true); return f + __builtin_bit_cast(float, t); }
    { int t = __builtin_amdgcn_update_dpp(0, __builtin_bit_cast(int, f), 0x143, 0xc, 0xf, true); return f + __builtin_bit_cast(float, t); }
}

// full 64-lane sum, result broadcast to all lanes
static __device__ __forceinline__ float wave_sum64(float f) {
    f = dpp_add_step(f, 0x111, 0xf);
    f = dpp_add_step(f, 0x112, 0xf);
    f = dpp_add_step(f, 0x114, 0xf);
    f = dpp_add_step(f, 0x118, 0xf);
    f = dpp_add_step(f, 0x142, 0xa);   // row_bcast15 -> rows 1,3 ; lane31/63 = half sums
    f = dpp_add_step(f, 0x143, 0xc);   // row_bcast31 -> rows 2,3 ; lane63 = total
    return __builtin_bit_cast(float, __builtin_amdgcn_readlane(__builtin_bit_cast(int, f), 63));
}

// per-32-lane-half sum, each lane gets its half's total
static __device__ __forceinline__ float half_sum32(float f, int half) {
    f = dpp_add_step(f, 0x111, 0xf);
    f = dpp_add_step(f, 0x112, 0xf);
    f = dpp_add_step(f, 0x114, 0xf);
    f = dpp_add_step(f, 0x118, 0xf);
    f = dpp_add_step(f, 0x142, 0xa);
    float s0 = __builtin_bit_cast(float, __builtin_amdgcn_readlane(__builtin_bit_cast(int, f), 31));
    float s1 = __builtin_bit_cast(float, __builtin_amdgcn_readlane(__builtin_bit_cast(int, f), 63));
    return half ? s1 : s0;
}

static __device__ __forceinline__ bf16x8 ld_lds8(const __bf16* p) {
    union { bf16x8 v; unsigned long long q[2]; } u;
    u.q[0] = *(const unsigned long long*)(p);
    u.q[1] = *(const unsigned long long*)(p + 4);
    return u.v;
}

// ---------------- mask dtype detection (int32 vs packed int8 bool) ----------------
__global__ __launch_bounds__(256) void k_detect_mask(const int* __restrict__ mask_w,
                                                     int* __restrict__ flag) {
    __shared__ int bad;
    if (threadIdx.x == 0) bad = 0;
    __syncthreads();
    int local = 0;
    for (int i = threadIdx.x; i < 16384; i += 256) {
        int v = mask_w[i];
        if (v != 0 && v != 1) local = 1;
    }
    if (local) atomicOr(&bad, 1);
    __syncthreads();
    if (threadIdx.x == 0) *flag = bad;   // 1 => data is packed int8 bools
}

static __device__ __forceinline__ int read_mask(const int* mw, int is_i8, int idx) {
    if (is_i8) return (int)((const unsigned char*)mw)[idx];
    return mw[idx];
}

// ---------------- Wo -> bf16 hi/lo, layout [o][144] (K padded 129->144 with zeros) ----------------
__global__ __launch_bounds__(256) void k_prep_wo(const float* __restrict__ Wo,
                                                 __bf16* __restrict__ Woh,
                                                 __bf16* __restrict__ Wol) {
    int idx = blockIdx.x * 256 + threadIdx.x;
    if (idx >= 128 * 144) return;
    int o = idx / 144, d = idx - o * 144;
    float v = (d < DP1) ? Wo[o * DP1 + d] : 0.f;
    __bf16 h = (__bf16)v;
    Woh[idx] = h;
    Wol[idx] = (__bf16)(v - (float)h);
}

// ---------------- embedding + Lorentz expmap0 -> bf16 hi/lo rows + comp0/comp128 f32 ----------------
__global__ __launch_bounds__(256) void k_prep(const int* __restrict__ tok,
                                              const float* __restrict__ emb,
                                              __bf16* __restrict__ Xh, __bf16* __restrict__ Xl,
                                              float* __restrict__ X0g, float* __restrict__ X128g) {
    __shared__ float Xf[64][132];
    const int t = threadIdx.x, w = t >> 6, l = t & 63;
    const int base = blockIdx.x * 64;
    for (int it = 0; it < 16; ++it) {
        const int tk = w * 16 + it;
        const int id = tok[base + tk];
        const float2 v = ((const float2*)(emb + (size_t)id * D_))[l];
        float s = wave_sum64(v.x * v.x + v.y * v.y);
        float nv = fmaxf(sqrtf(s), 1e-7f);
        float a = SCf * nv;
        float a2 = a * a;
        float shc, ch;
        if (a < 0.5f) {
            shc = 1.f + a2 * (1.f/6.f) * (1.f + a2 * (1.f/20.f) * (1.f + a2 * (1.f/42.f)));
            ch  = 1.f + a2 * 0.5f * (1.f + a2 * (1.f/12.f) * (1.f + a2 * (1.f/30.f)));
        } else {
            float ea = __expf(a), ei = 1.f / ea;
            ch = 0.5f * (ea + ei);
            shc = 0.5f * (ea - ei) / a;
        }
        Xf[tk][1 + 2 * l] = v.x * shc;
        Xf[tk][2 + 2 * l] = v.y * shc;
        if (l == 0) Xf[tk][0] = ch / SCf;
    }
    __syncthreads();
    const int tk2 = t >> 2, dg = (t & 3) * 32;
    for (int i = 0; i < 32; i += 8) {
        bf16x8 hv, lv;
        #pragma unroll
        for (int j = 0; j < 8; ++j) {
            float f = Xf[tk2][dg + i + j];
            __bf16 h = (__bf16)f;
            hv[j] = h;
            lv[j] = (__bf16)(f - (float)h);
        }
        *(bf16x8*)(Xh + (size_t)(base + tk2) * D_ + dg + i) = hv;
        *(bf16x8*)(Xl + (size_t)(base + tk2) * D_ + dg + i) = lv;
    }
    if (t < 64) {
        X0g[base + t]   = Xf[t][0];
        X128g[base + t] = Xf[t][D_];
    }
}

// ---------------- fused MFMA attention: scores + exp + centroid + renorm + projection + expmap ----------------
__global__ __launch_bounds__(256, 2) void k_attn(
        const __bf16* __restrict__ Xh, const __bf16* __restrict__ Xl,
        const float* __restrict__ X0g, const float* __restrict__ X128g,
        const int* __restrict__ mask, const int* __restrict__ mflag,
        const __bf16* __restrict__ Woh, const __bf16* __restrict__ Wol,
        const float* __restrict__ bo,
        float* __restrict__ Y, float* __restrict__ Y2) {
    extern __shared__ char smem[];
    __bf16* Krow = (__bf16*)smem;                   // 16896 B
    __bf16* XTb  = (__bf16*)(smem + 16896);         // 18432 B
    __bf16* Pb   = (__bf16*)(smem + 35328);         // 18432 B
    __shared__ float K0s[KT];
    __shared__ float K128s[KT];
    __shared__ int   Ms[KT];

    const int b    = blockIdx.y;
    const int qb   = blockIdx.x * QB;
    const int t    = threadIdx.x;
    const int w    = t >> 6;
    const int l    = t & 63;
    const int l31  = l & 31;
    const int half = l >> 5;
    const int is8  = *mflag;

    const size_t qrow = (size_t)(b * N_ + qb + w * 32 + l31);
    bf16x8 qfh[8], qfl[8];
    #pragma unroll
    for (int ks = 0; ks < 8; ++ks) {
        qfh[ks] = *(const bf16x8*)(Xh + qrow * D_ + ks * 16 + half * 8);
        qfl[ks] = *(const bf16x8*)(Xl + qrow * D_ + ks * 16 + half * 8);
    }
    float q0[16], q128[16];
    #pragma unroll
    for (int r = 0; r < 16; ++r) {
        const int qr = (r & 3) + 8 * (r >> 2) + 4 * half;
        q0[r]   = X0g[b * N_ + qb + w * 32 + qr];
        q128[r] = X128g[b * N_ + qb + w * 32 + qr];
    }

    f32x16 accM[4] = {};
    float  mu128p[16] = {};

    for (int kt = 0; kt < N_ / KT; ++kt) {
        __syncthreads();
        {
            const int key = t >> 3, ck = t & 7;
            const size_t krow = (size_t)(b * N_ + kt * KT + key);
            #pragma unroll
            for (int ch = 0; ch < 2; ++ch) {
                const int c0 = ck * 8 + 64 * ch;
                bf16x8 vh = *(const bf16x8*)(Xh + krow * D_ + c0);
                bf16x8 vl = *(const bf16x8*)(Xl + krow * D_ + c0);
                union { bf16x8 v; unsigned long long q[2]; } uh, ul;
                uh.v = vh; ul.v = vl;
                *(unsigned long long*)(Krow + key * 132 + c0)            = uh.q[0];
                *(unsigned long long*)(Krow + key * 132 + c0 + 4)        = uh.q[1];
                *(unsigned long long*)(Krow + 4224 + key * 132 + c0)     = ul.q[0];
                *(unsigned long long*)(Krow + 4224 + key * 132 + c0 + 4) = ul.q[1];
                #pragma unroll
                for (int j = 0; j < 8; ++j) {
                    XTb[(c0 + j) * 36 + key]        = vh[j];
                    XTb[4608 + (c0 + j) * 36 + key] = vl[j];
                }
            }
            if (t < KT) {
                K0s[t]   = X0g[b * N_ + kt * KT + t];
                K128s[t] = X128g[b * N_ + kt * KT + t];
                Ms[t]    = read_mask(mask, is8, b * N_ + kt * KT + t);
            }
        }
        __syncthreads();

        f32x16 accS = {};
        #pragma unroll
        for (int ks = 0; ks < 8; ++ks) {
            bf16x8 bh = ld_lds8(Krow + l31 * 132 + ks * 16 + half * 8);
            bf16x8 bl = ld_lds8(Krow + 4224 + l31 * 132 + ks * 16 + half * 8);
            accS = MFMA(qfh[ks], bh, accS);
            accS = MFMA(qfh[ks], bl, accS);
            accS = MFMA(qfl[ks], bh, accS);
        }
        const float k0v = K0s[l31], k128v = K128s[l31];
        const int   mv  = Ms[l31];
        #pragma unroll
        for (int r = 0; r < 16; ++r) {
            float sc = (2.f * q0[r] * k0v - accS[r] - q128[r] * k128v) * SCALE;
            float e  = mv ? __expf(sc) : 0.f;
            mu128p[r] += e * k128v;
            __bf16 eh = (__bf16)e;
            __bf16 el = (__bf16)(e - (float)eh);
            const int qr = (r & 3) + 8 * (r >> 2) + 4 * half;
            Pb[(w * 2 + 0) * 1152 + qr * 36 + l31] = eh;
            Pb[(w * 2 + 1) * 1152 + qr * 36 + l31] = el;
        }

        #pragma unroll
        for (int ks = 0; ks < 2; ++ks) {
            bf16x8 ah = ld_lds8(Pb + (w * 2 + 0) * 1152 + l31 * 36 + ks * 16 + half * 8);
            bf16x8 al = ld_lds8(Pb + (w * 2 + 1) * 1152 + l31 * 36 + ks * 16 + half * 8);
            #pragma unroll
            for (int nt = 0; nt < 4; ++nt) {
                bf16x8 bh = ld_lds8(XTb + (nt * 32 + l31) * 36 + ks * 16 + half * 8);
                bf16x8 bl = ld_lds8(XTb + 4608 + (nt * 32 + l31) * 36 + ks * 16 + half * 8);
                accM[nt] = MFMA(ah, bh, accM[nt]);
                accM[nt] = MFMA(ah, bl, accM[nt]);
                accM[nt] = MFMA(al, bh, accM[nt]);
            }
        }
    }

    #pragma unroll
    for (int r = 0; r < 16; ++r) mu128p[r] = half_sum32(mu128p[r], half);
    float rno[16];
    #pragma unroll
    for (int r = 0; r < 16; ++r) {
        float p = 0.f;
        #pragma unroll
        for (int nt = 0; nt < 4; ++nt) p += accM[nt][r] * accM[nt][r];
        if (l31 == 0) p -= 2.f * accM[0][r] * accM[0][r];
        p = half_sum32(p, half);
        float negI = -(p + mu128p[r] * mu128p[r]);
        negI = fmaxf(negI, 1e-7f);
        rno[r] = 1.f / (SCf * sqrtf(negI));
    }
    #pragma unroll
    for (int nt = 0; nt < 4; ++nt)
        #pragma unroll
        for (int r = 0; r < 16; ++r) accM[nt][r] *= rno[r];
    #pragma unroll
    for (int r = 0; r < 16; ++r) mu128p[r] *= rno[r];

    __syncthreads();
    __bf16* MuA = (__bf16*)smem + w * (32 * 148);
    #pragma unroll
    for (int r = 0; r < 16; ++r) {
        const int qr = (r & 3) + 8 * (r >> 2) + 4 * half;
        #pragma unroll
        for (int nt = 0; nt < 4; ++nt)
            MuA[qr * 148 + nt * 32 + l31] = (__bf16)accM[nt][r];
        if (l31 == 0) MuA[qr * 148 + 128] = (__bf16)mu128p[r];
        if (l31 >= 1 && l31 <= 15) MuA[qr * 148 + 128 + l31] = (__bf16)0.f;
    }
    bf16x8 Ah[9];
    #pragma unroll
    for (int ks = 0; ks < 9; ++ks) Ah[ks] = ld_lds8(MuA + l31 * 148 + ks * 16 + half * 8);
    #pragma unroll
    for (int r = 0; r < 16; ++r) {
        const int qr = (r & 3) + 8 * (r >> 2) + 4 * half;
        #pragma unroll
        for (int nt = 0; nt < 4; ++nt) {
            float m = accM[nt][r];
            MuA[qr * 148 + nt * 32 + l31] = (__bf16)(m - (float)(__bf16)m);
        }
        if (l31 == 0) {
            float m = mu128p[r];
            MuA[qr * 148 + 128] = (__bf16)(m - (float)(__bf16)m);
        }
    }
    bf16x8 Al[9];
    #pragma unroll
    for (int ks = 0; ks < 9; ++ks) Al[ks] = ld_lds8(MuA + l31 * 148 + ks * 16 + half * 8);

    f32x16 accU[4] = {};
    #pragma unroll
    for (int ks = 0; ks < 9; ++ks) {
        #pragma unroll
        for (int nt = 0; nt < 4; ++nt) {
            bf16x8 bh = *(const bf16x8*)(Woh + (size_t)(nt * 32 + l31) * 144 + ks * 16 + half * 8);
            bf16x8 bl = *(const bf16x8*)(Wol + (size_t)(nt * 32 + l31) * 144 + ks * 16 + half * 8);
            accU[nt] = MFMA(Ah[ks], bh, accU[nt]);
            accU[nt] = MFMA(Ah[ks], bl, accU[nt]);
            accU[nt] = MFMA(Al[ks], bh, accU[nt]);
        }
    }

    float bov[4];
    #pragma unroll
    for (int nt = 0; nt < 4; ++nt) bov[nt] = bo[nt * 32 + l31];
    #pragma unroll
    for (int r = 0; r < 16; ++r) {
        float p = 0.f;
        #pragma unroll
        for (int nt = 0; nt < 4; ++nt) {
            float uv = accU[nt][r] + bov[nt];
            accU[nt][r] = uv;
            p += uv * uv;
        }
        float nn = half_sum32(p, half);
        float nu = fmaxf(sqrtf(nn), 1e-7f);
        float aa = SCf * nu;
        float cf = tanhf(aa) / aa;
        const int qr = (r & 3) + 8 * (r >> 2) + 4 * half;
        const size_t row = (size_t)(b * N_ + qb + w * 32 + qr);
        #pragma unroll
        for (int nt = 0; nt < 4; ++nt)
            Y[row * D_ + nt * 32 + l31] = accU[nt][r] * cf;
        if (l31 == 0) Y2[row] = nn * cf * cf;
    }
}

// ---------------- sequential Mobius fold: homogeneous (division-free) recurrence ----------------
// acc = U/D, x2 = P/D^2.  Mobius add becomes polynomial:
//   Ahat = D*(1+c*py2) + 2c*<U,y> ; Bhat = D^2 - c*P ; dhat = D^2 + 2c*D*<U,y> + c^2*P*py2
//   U' = Ahat*U + Bhat*y ; D' = dhat ; P' = Ahat^2*P + 2*Ahat*Bhat*<U,y> + Bhat^2*py2
// Exact power-of-2 rescale every 4 steps keeps exponents bounded (lossless).
__global__ __launch_bounds__(64) void k_pool(const float* __restrict__ Y,
                                             const float* __restrict__ Y2,
                                             const int* __restrict__ mask,
                                             const int* __restrict__ mflag,
                                             const float* __restrict__ Wf,
                                             const float* __restrict__ bf_,
                                             float* __restrict__ out) {
    __shared__ float         py2s[N_];
    __shared__ unsigned char ms[N_];
    __shared__ double        vb[D_];
    const int b = blockIdx.x, l = threadIdx.x;
    const int is8 = *mflag;
    const double c  = 0.1;
    const double c2 = 0.01;
    const double SCd = 0.31622776601683794;

    for (int i = l; i < N_; i += 64) {
        py2s[i] = Y2[b * N_ + i];
        ms[i]   = (unsigned char)read_mask(mask, is8, b * N_ + i);
    }
    __syncthreads();

    const float2* __restrict__ Yp = (const float2*)(Y + (size_t)b * N_ * D_) + l;

    constexpr int PF = 16;
    float2 buf[PF];
    #pragma unroll
    for (int k = 0; k < PF; ++k) buf[k] = Yp[(size_t)k * 64];

    float  u0 = 0.f, u1 = 0.f;          // U components 2l, 2l+1 (f32)
    double Dh = 1.0, P = 0.0;           // homogeneous denominator, |U|^2
    int cnt = 0;

    for (int i0 = 0; i0 < N_; i0 += PF) {
        #pragma unroll
        for (int k = 0; k < PF; ++k) {
            const int i = i0 + k;
            const float2 yv = buf[k];
            const int inx = i + PF;
            if (inx < N_) buf[k] = Yp[(size_t)inx * 64];

            const double py2  = (double)py2s[i];
            const bool   m    = ms[i] != 0;
            const double onep = fma(c, py2, 1.0);        // 1 + c*py2  (off-chain)
            const double Dsq  = Dh * Dh;                 // off-chain (dep only on Dh)
            const double Bh   = fma(-c, P, Dsq);         // Bhat (off-chain)
            const double tP   = (c2 * py2) * P;          // off-chain

            // --- critical chain: dot -> reduce -> Ahat -> cvt -> U update ---
            const float  red = wave_sum64(fmaf(u0, yv.x, u1 * yv.y));
            const double puy = (double)red;
            const double Ah2 = fma(0.2, puy, Dh * onep); // Ahat = D*onep + 2c*puy
            const float Af = m ? (float)Ah2 : 1.0f;
            const float Bf = m ? (float)Bh  : 0.0f;
            u0 = fmaf(Af, u0, Bf * yv.x);
            u1 = fmaf(Af, u1, Bf * yv.y);

            // --- slack path (consumed next iteration / at rescale) ---
            double dh = fma(Dh, fma(0.2, puy, Dh), tP);  // dhat
            dh = fmax(dh, 1e-12 * Dsq);                  // ref's den clamp (never triggers)
            const double Pn = fma(Ah2, fma(Ah2, P, (2.0 * Bh) * puy), (Bh * Bh) * py2);
            Dh = m ? dh : Dh;
            P  = m ? Pn : P;
            cnt += m ? 1 : 0;

            if ((k & 3) == 3) {                          // exact 2^-e rescale (lossless)
                const int e = ilogb(Dh);
                Dh = ldexp(Dh, -e);
                P  = ldexp(P, -2 * e);
                u0 = ldexpf(u0, -e);
                u1 = ldexpf(u1, -e);
            }
        }
    }

    // de-homogenize: acc = U/D, x2 = P/D^2  (single division after the loop)
    const double sD = 1.0 / Dh;
    double a0 = sD * (double)u0, a1 = sD * (double)u1;
    double n2 = fmax(P * (sD * sD), 0.0);
    double n = sqrt(n2);
    double tt = SCd * n;
    tt = fmin(fmax(tt, 1e-7), 1.0 - 1e-6);
    int cm = cnt > 0 ? cnt : 1;
    float rf = (float)(1.0 / (double)cm);        // ref casts r to float32
    double r = (double)rf;
    double dv = fmax(SCd * n, 1e-7);
    double f = tanh(r * atanh(tt)) / dv;
    double p0 = a0 * f, p1 = a1 * f;
    double q2;
    if (cnt == 0) {                              // fallback: first token's y
        float2 y0v = *(const float2*)(Y + (size_t)(b * N_) * D_ + 2 * l);
        p0 = y0v.x; p1 = y0v.y;
        q2 = (double)Y2[b * N_];
    } else {
        q2 = f * f * n2;
    }
    double npn = fmax(sqrt(q2), 1e-7);
    double t2 = fmin(fmax(SCd * npn, 1e-7), 1.0 - 1e-6);
    double f2 = atanh(t2) / (SCd * npn);
    vb[2 * l]     = p0 * f2;
    vb[2 * l + 1] = p1 * f2;
    __syncthreads();

    if (l < NC_) {
        double o = (double)bf_[l];
        for (int d = 0; d < D_; ++d) o += vb[d] * (double)Wf[l * D_ + d];
        out[b * NC_ + l] = (float)o;
    }
}

extern "C" void kernel_launch(void* const* d_in, const int* in_sizes, int n_in,
                              void* d_out, int out_size, void* d_ws, size_t ws_size,
                              hipStream_t stream) {
    const int*   tok  = (const int*)d_in[0];
    const int*   mask = (const int*)d_in[1];
    const float* emb  = (const float*)d_in[2];
    const float* Wo   = (const float*)d_in[3];
    const float* bo   = (const float*)d_in[4];
    const float* Wf   = (const float*)d_in[5];
    const float* bf_  = (const float*)d_in[6];
    float* out = (float*)d_out;

    char* wsb = (char*)d_ws;
    __bf16* Xh   = (__bf16*)wsb;                              // 16,777,216 B
    __bf16* Xl   = (__bf16*)(wsb + 16777216);                 // 16,777,216 B
    float*  X0g  = (float*)(wsb + 33554432);                  //    262,144 B
    float*  X128g= (float*)(wsb + 33816576);                  //    262,144 B
    __bf16* Woh  = (__bf16*)(wsb + 34078720);                 //     36,864 B
    __bf16* Wol  = (__bf16*)(wsb + 34115584);                 //     36,864 B
    float*  Y    = (float*)(wsb + 34152448);                  // 33,554,432 B
    float*  Y2   = (float*)(wsb + 67706880);                  //    262,144 B
    int*    flag = (int*)(wsb + 67969024);                    // total ~67.97 MB

    k_detect_mask<<<dim3(1), dim3(256), 0, stream>>>(mask, flag);
    k_prep_wo<<<dim3(72), dim3(256), 0, stream>>>(Wo, Woh, Wol);
    k_prep<<<dim3(B_ * N_ / 64), dim3(256), 0, stream>>>(tok, emb, Xh, Xl, X0g, X128g);
    k_attn<<<dim3(N_ / QB, B_), dim3(256), 53760, stream>>>(Xh, Xl, X0g, X128g, mask, flag,
                                                            Woh, Wol, bo, Y, Y2);
    k_pool<<<dim3(B_), dim3(64), 0, stream>>>(Y, Y2, mask, flag, Wf, bf_, out);
}